// Round 1
// baseline (2424.586 us; speedup 1.0000x reference)
//
#include <hip/hip_runtime.h>
#include <math.h>

// ---------------------------------------------------------------------------
// FastImageMamba forward, fp32 baseline.
// B=4, DM=256, NL=4, NC=1000, DI=512, NS=16, DTR=32, K=4, L=1024 (32x32), H=W=64
// ---------------------------------------------------------------------------

#define BN_RSQ 0.99999500003749969f   // 1/sqrt(1+1e-5)

__device__ __forceinline__ float gelu_f(float v) {
    return 0.5f * v * (1.0f + erff(v * 0.70710678118654752f));
}
__device__ __forceinline__ float softplus_f(float v) {
    return (v > 20.f) ? v : log1pf(expf(v));
}

// ---------------------------------------------------------------------------
// Direct 3x3 conv (stride1 pad1, NCHW, H=W=64) + bias + BN(running stats) + GELU
// grid: (B*OC, 4); block 256.  Each thread: 4 outputs along x, weights in LDS.
// ---------------------------------------------------------------------------
__global__ __launch_bounds__(256) void conv3x3_bn_gelu(
    const float* __restrict__ in, const float* __restrict__ wt,
    const float* __restrict__ cb, const float* __restrict__ g,
    const float* __restrict__ bb, float* __restrict__ out, int IC, int OC)
{
    __shared__ float ws[128 * 9];
    int t = threadIdx.x;
    int oc = blockIdx.x % OC, b = blockIdx.x / OC;
    int y0 = blockIdx.y * 16;
    int nw = IC * 9;
    for (int i = t; i < nw; i += 256) ws[i] = wt[(size_t)oc * nw + i];
    __syncthreads();
    int xq = t & 15, yy = t >> 4;
    int y = y0 + yy, x0 = xq * 4;
    float a0 = 0.f, a1 = 0.f, a2 = 0.f, a3 = 0.f;
    const float* inb = in + (size_t)b * IC * 4096;
    for (int ic = 0; ic < IC; ++ic) {
        const float* plane = inb + (size_t)ic * 4096;
        const float* wr = &ws[ic * 9];
        #pragma unroll
        for (int ky = 0; ky < 3; ++ky) {
            int gy = y + ky - 1;
            if ((unsigned)gy < 64u) {
                const float* row = plane + gy * 64;
                float iv0 = (x0 > 0) ? row[x0 - 1] : 0.f;
                float4 mid = *(const float4*)(row + x0);
                float iv5 = (x0 + 4 < 64) ? row[x0 + 4] : 0.f;
                float w0 = wr[ky * 3 + 0], w1 = wr[ky * 3 + 1], w2 = wr[ky * 3 + 2];
                a0 += iv0   * w0 + mid.x * w1 + mid.y * w2;
                a1 += mid.x * w0 + mid.y * w1 + mid.z * w2;
                a2 += mid.y * w0 + mid.z * w1 + mid.w * w2;
                a3 += mid.z * w0 + mid.w * w1 + iv5   * w2;
            }
        }
    }
    float sc = g[oc] * BN_RSQ, sh = bb[oc], cbv = cb[oc];
    float4 o;
    o.x = gelu_f((a0 + cbv) * sc + sh);
    o.y = gelu_f((a1 + cbv) * sc + sh);
    o.z = gelu_f((a2 + cbv) * sc + sh);
    o.w = gelu_f((a3 + cbv) * sc + sh);
    *(float4*)(out + (((size_t)b * OC + oc) * 64 + y) * 64 + x0) = o;
}

// ---------------------------------------------------------------------------
// im2col for the 2x2 stride-2 patch conv: Ap[m][k], m=b*1024+oy*32+ox,
// k=ic*4+ky*2+kx (matches pw's [oc][ic][ky][kx] row-major layout).
// LDS transpose so reads and writes are both reasonably coalesced.
// grid (64 m-tiles, 16 k-tiles); block 256.
// ---------------------------------------------------------------------------
__global__ __launch_bounds__(256) void im2col_patch_kernel(
    const float* __restrict__ h2, float* __restrict__ Ap)
{
    __shared__ float T[64][65];
    int t = threadIdx.x;
    int m0 = blockIdx.x * 64, k0 = blockIdx.y * 64;
    int ml = t & 63, kq = t >> 6;
    int m = m0 + ml;
    int b = m >> 10, rem = m & 1023;
    int oy = rem >> 5, ox = rem & 31;
    for (int kl = kq * 16; kl < kq * 16 + 16; ++kl) {
        int k = k0 + kl;
        int ic = k >> 2, r = k & 3, ky = r >> 1, kx = r & 1;
        T[kl][ml] = h2[(((size_t)(b * 256 + ic)) * 64 + oy * 2 + ky) * 64 + ox * 2 + kx];
    }
    __syncthreads();
    int k4 = (t & 15) * 4, mr = t >> 4;
    #pragma unroll
    for (int j = 0; j < 4; ++j) {
        int mm = j * 16 + mr;
        float4 vv = make_float4(T[k4][mm], T[k4 + 1][mm], T[k4 + 2][mm], T[k4 + 3][mm]);
        *(float4*)(Ap + (size_t)(m0 + mm) * 1024 + k0 + k4) = vv;
    }
}

// ---------------------------------------------------------------------------
// Generic tiled fp32 GEMM: C[M,N] = act( bn( A[M,K] @ W[N,K]^T + bias ) )
// act: 0 none, 1 gelu, 2 softplus. bn applied iff bnG != null (scale g*BN_RSQ, shift bnB).
// smode: 0 -> C[m*ldc+n]; 1 -> delta store C[(b*N+n)*1024 + l], m=b*1024+l.
// 256 threads; BM*BK/4==256, BN*BK/4==256; thread grid 16x16, micro TMxTN.
// ---------------------------------------------------------------------------
template<int BM, int BN, int BK, int TM, int TN>
__global__ __launch_bounds__(256) void gemm_kernel(
    const float* __restrict__ A, int lda,
    const float* __restrict__ W, int ldw,
    const float* __restrict__ bias,
    const float* __restrict__ bnG, const float* __restrict__ bnB,
    float* __restrict__ C, int ldc,
    int M, int N, int K, int act, int smode)
{
    static_assert(BM * BK / 4 == 256 && BN * BK / 4 == 256, "staging shape");
    __shared__ float As[BK][BM + 4];
    __shared__ float Bs[BK][BN + 4];
    int t = threadIdx.x;
    int m0 = blockIdx.x * BM, n0 = blockIdx.y * BN;
    float acc[TM][TN];
    #pragma unroll
    for (int i = 0; i < TM; i++)
        #pragma unroll
        for (int j = 0; j < TN; j++) acc[i][j] = 0.f;
    const int LPR = BK / 4;
    int lr = t / LPR, lc4 = (t % LPR) * 4;
    int ty = t >> 4, tx = t & 15;
    for (int k0 = 0; k0 < K; k0 += BK) {
        float4 va = make_float4(0.f, 0.f, 0.f, 0.f);
        float4 vb = make_float4(0.f, 0.f, 0.f, 0.f);
        int ma = m0 + lr;
        if (ma < M) va = *(const float4*)(A + (size_t)ma * lda + k0 + lc4);
        int nb = n0 + lr;
        if (nb < N) vb = *(const float4*)(W + (size_t)nb * ldw + k0 + lc4);
        __syncthreads();
        As[lc4 + 0][lr] = va.x; As[lc4 + 1][lr] = va.y;
        As[lc4 + 2][lr] = va.z; As[lc4 + 3][lr] = va.w;
        Bs[lc4 + 0][lr] = vb.x; Bs[lc4 + 1][lr] = vb.y;
        Bs[lc4 + 2][lr] = vb.z; Bs[lc4 + 3][lr] = vb.w;
        __syncthreads();
        #pragma unroll
        for (int kk = 0; kk < BK; ++kk) {
            float a[TM], bfr[TN];
            #pragma unroll
            for (int i = 0; i < TM; i += 4)
                *(float4*)&a[i] = *(const float4*)&As[kk][ty * TM + i];
            #pragma unroll
            for (int j = 0; j < TN; j += 4)
                *(float4*)&bfr[j] = *(const float4*)&Bs[kk][tx * TN + j];
            #pragma unroll
            for (int i = 0; i < TM; i++)
                #pragma unroll
                for (int j = 0; j < TN; j++) acc[i][j] = fmaf(a[i], bfr[j], acc[i][j]);
        }
    }
    #pragma unroll
    for (int i = 0; i < TM; i++) {
        int m = m0 + ty * TM + i;
        if (m >= M) continue;
        int bI = m >> 10, lI = m & 1023;
        #pragma unroll
        for (int j = 0; j < TN; j++) {
            int n = n0 + tx * TN + j;
            if (n >= N) continue;
            float v = acc[i][j];
            if (bias) v += bias[n];
            if (bnG)  v = v * (bnG[n] * BN_RSQ) + bnB[n];
            if (act == 1) v = gelu_f(v);
            else if (act == 2) v = softplus_f(v);
            if (smode == 0) C[(size_t)m * ldc + n] = v;
            else            C[((size_t)(bI * N + n) << 10) + lI] = v;
        }
    }
}

// ---------------------------------------------------------------------------
// Depthwise conv1d (K=4, pad(1,2), correlation) on xi = xr[:, :, 0:512].
// Dual-layout store: xl[b,l,512] (for GEMMs) and u[b,d,l] (for the scan).
// grid 512 = b(4) * l-tiles(16) * d-tiles(8); block 256. LDS transpose tiles.
// ---------------------------------------------------------------------------
__global__ __launch_bounds__(256) void dwconv_dual(
    const float* __restrict__ xr, const float* __restrict__ cw,
    const float* __restrict__ cb, float* __restrict__ xl, float* __restrict__ u)
{
    __shared__ float tin[68][65];
    __shared__ float tout[64][65];
    int t = threadIdx.x;
    int bid = blockIdx.x;
    int dt_ = bid & 7, lt = (bid >> 3) & 15, b = bid >> 7;
    int d0 = dt_ * 64, l0 = lt * 64;
    int lane = t & 63, grp = t >> 6;
    for (int r = grp; r < 68; r += 4) {
        int l = l0 + r - 1;
        float v = 0.f;
        if ((unsigned)l < 1024u) v = xr[(size_t)(b * 1024 + l) * 1024 + d0 + lane];
        tin[r][lane] = v;
    }
    __syncthreads();
    {
        int d = d0 + lane;
        float w0 = cw[d * 4 + 0], w1 = cw[d * 4 + 1], w2 = cw[d * 4 + 2], w3 = cw[d * 4 + 3];
        float bv = cb[d];
        int li0 = grp * 16;
        #pragma unroll
        for (int q = 0; q < 16; ++q) {
            int li = li0 + q;
            float v = bv + w0 * tin[li][lane] + w1 * tin[li + 1][lane]
                         + w2 * tin[li + 2][lane] + w3 * tin[li + 3][lane];
            tout[li][lane] = v;
        }
    }
    __syncthreads();
    for (int r = grp; r < 64; r += 4)
        xl[(size_t)(b * 1024 + l0 + r) * 512 + d0 + lane] = tout[r][lane];
    for (int r = grp; r < 64; r += 4)
        u[(size_t)(b * 512 + d0 + r) * 1024 + l0 + lane] = tout[lane][r];
}

// ---------------------------------------------------------------------------
// Transpose B/C slices of xdbl[b,l,64] -> Bt/Ct [b,16,1024]
// ---------------------------------------------------------------------------
__global__ void tbc_kernel(const float* __restrict__ xdbl,
                           float* __restrict__ Bt, float* __restrict__ Ct)
{
    int idx = blockIdx.x * 256 + threadIdx.x;   // 65536 = 4*16*1024
    int l = idx & 1023, r = idx >> 10;
    int n = r & 15, b = r >> 4;
    const float* src = xdbl + (size_t)((b << 10) + l) * 64;
    Bt[idx] = src[32 + n];
    Ct[idx] = src[48 + n];
}

// ---------------------------------------------------------------------------
// Selective scan. One wave per (b, group of 4 d). lane = dl*16 + n.
// h_n(l) = exp(delta*A[d,n])*h + delta*B[b,n,l]*u[b,d,l];  y = sum_n h*C + u*D
// y written in [b, l, 512] layout for the out_proj GEMM.
// grid 128 x 256 threads (512 waves).
// ---------------------------------------------------------------------------
__global__ __launch_bounds__(256) void scan_kernel(
    const float* __restrict__ delta, const float* __restrict__ u,
    const float* __restrict__ Bt, const float* __restrict__ Ct,
    const float* __restrict__ alog, const float* __restrict__ dssm,
    float* __restrict__ y)
{
    int wid = (blockIdx.x * 256 + threadIdx.x) >> 6;
    int lane = threadIdx.x & 63;
    int b = wid >> 7, dg = wid & 127;
    int dl = lane >> 4, n = lane & 15;
    int d = dg * 4 + dl;
    float Ac = -__expf(alog[d * 16 + n]);
    float Dd = dssm[d];
    const float4* dp = (const float4*)(delta + ((size_t)(b * 512 + d) << 10));
    const float4* up = (const float4*)(u + ((size_t)(b * 512 + d) << 10));
    const float4* Bp = (const float4*)(Bt + ((size_t)(b * 16 + n) << 10));
    const float4* Cp = (const float4*)(Ct + ((size_t)(b * 16 + n) << 10));
    float* yp = y + ((size_t)b << 19) + d;
    float h = 0.f;
    float4 de = dp[0], uu = up[0], Bv = Bp[0], Cv = Cp[0];
    for (int it = 0; it < 256; ++it) {
        int nx = (it < 255) ? it + 1 : 255;
        float4 de2 = dp[nx], uu2 = up[nx], Bv2 = Bp[nx], Cv2 = Cp[nx];
        float p0, p1, p2, p3;
        h = __expf(de.x * Ac) * h + de.x * Bv.x * uu.x; p0 = h * Cv.x;
        h = __expf(de.y * Ac) * h + de.y * Bv.y * uu.y; p1 = h * Cv.y;
        h = __expf(de.z * Ac) * h + de.z * Bv.z * uu.z; p2 = h * Cv.z;
        h = __expf(de.w * Ac) * h + de.w * Bv.w * uu.w; p3 = h * Cv.w;
        #pragma unroll
        for (int off = 1; off < 16; off <<= 1) {
            p0 += __shfl_xor(p0, off);
            p1 += __shfl_xor(p1, off);
            p2 += __shfl_xor(p2, off);
            p3 += __shfl_xor(p3, off);
        }
        if (n == 0) {
            size_t l = (size_t)it * 4;
            yp[(l + 0) * 512] = p0 + uu.x * Dd;
            yp[(l + 1) * 512] = p1 + uu.y * Dd;
            yp[(l + 2) * 512] = p2 + uu.z * Dd;
            yp[(l + 3) * 512] = p3 + uu.w * Dd;
        }
        de = de2; uu = uu2; Bv = Bv2; Cv = Cv2;
    }
}

// y[b,l,d] *= silu(res) with res = xr[b,l,512+d]
__global__ void gate_kernel(float* __restrict__ y, const float* __restrict__ xr)
{
    int idx = blockIdx.x * 256 + threadIdx.x;   // 2,097,152
    int d = idx & 511;
    int bl = idx >> 9;
    float r = xr[(size_t)bl * 1024 + 512 + d];
    float s = r / (1.f + __expf(-r));
    y[idx] *= s;
}

// s[row] = LN(o[row])*g + b + s[row]; one wave per 256-elem row
__global__ __launch_bounds__(256) void ln_res_kernel(
    const float* __restrict__ o, const float* __restrict__ g,
    const float* __restrict__ bb, float* __restrict__ s)
{
    int row = blockIdx.x * 4 + (threadIdx.x >> 6);
    int lane = threadIdx.x & 63;
    const float4* orow = (const float4*)(o + (size_t)row * 256);
    float4 v = orow[lane];
    float sum = v.x + v.y + v.z + v.w;
    float sq = v.x * v.x + v.y * v.y + v.z * v.z + v.w * v.w;
    #pragma unroll
    for (int off = 1; off < 64; off <<= 1) {
        sum += __shfl_xor(sum, off);
        sq += __shfl_xor(sq, off);
    }
    float m = sum * (1.f / 256.f);
    float var = sq * (1.f / 256.f) - m * m;
    float rstd = rsqrtf(var + 1e-5f);
    float4 gg = ((const float4*)g)[lane];
    float4 bv = ((const float4*)bb)[lane];
    float4* srow = (float4*)(s + (size_t)row * 256);
    float4 sv = srow[lane];
    sv.x += (v.x - m) * rstd * gg.x + bv.x;
    sv.y += (v.y - m) * rstd * gg.y + bv.y;
    sv.z += (v.z - m) * rstd * gg.z + bv.z;
    sv.w += (v.w - m) * rstd * gg.w + bv.w;
    srow[lane] = sv;
}

// mean over l (1024) then LN over 256 channels. grid 4 x 256.
__global__ __launch_bounds__(256) void pool_ln_kernel(
    const float* __restrict__ s, const float* __restrict__ nw,
    const float* __restrict__ nb, float* __restrict__ sln)
{
    int b = blockIdx.x, c = threadIdx.x;
    const float* p = s + (size_t)b * 262144 + c;
    float acc = 0.f;
    for (int l = 0; l < 1024; ++l) acc += p[(size_t)l * 256];
    float pooled = acc * (1.f / 1024.f);
    __shared__ float rs[4], rq[4];
    float sum = pooled, sq = pooled * pooled;
    #pragma unroll
    for (int off = 1; off < 64; off <<= 1) {
        sum += __shfl_xor(sum, off);
        sq += __shfl_xor(sq, off);
    }
    int w = threadIdx.x >> 6;
    if ((threadIdx.x & 63) == 0) { rs[w] = sum; rq[w] = sq; }
    __syncthreads();
    sum = rs[0] + rs[1] + rs[2] + rs[3];
    sq = rq[0] + rq[1] + rq[2] + rq[3];
    float m = sum * (1.f / 256.f);
    float var = sq * (1.f / 256.f) - m * m;
    float rstd = rsqrtf(var + 1e-5f);
    sln[b * 256 + c] = (pooled - m) * rstd * nw[c] + nb[c];
}

// softmax over 1000 logits per b; logits at out[0:4000], probs at out[4000:8000]
__global__ __launch_bounds__(256) void softmax_kernel(float* __restrict__ out)
{
    int b = threadIdx.x >> 6, lane = threadIdx.x & 63;
    const float* lg = out + b * 1000;
    float v[16];
    float mx = -1e30f;
    #pragma unroll
    for (int j = 0; j < 16; ++j) {
        int i = lane + j * 64;
        v[j] = (i < 1000) ? lg[i] : -1e30f;
        mx = fmaxf(mx, v[j]);
    }
    #pragma unroll
    for (int off = 1; off < 64; off <<= 1) mx = fmaxf(mx, __shfl_xor(mx, off));
    float sum = 0.f;
    #pragma unroll
    for (int j = 0; j < 16; ++j) {
        int i = lane + j * 64;
        if (i < 1000) { v[j] = __expf(v[j] - mx); sum += v[j]; }
    }
    #pragma unroll
    for (int off = 1; off < 64; off <<= 1) sum += __shfl_xor(sum, off);
    float inv = 1.f / sum;
    float* so = out + 4000 + b * 1000;
    #pragma unroll
    for (int j = 0; j < 16; ++j) {
        int i = lane + j * 64;
        if (i < 1000) so[i] = v[j] * inv;
    }
}

// ---------------------------------------------------------------------------
extern "C" void kernel_launch(void* const* d_in, const int* in_sizes, int n_in,
                              void* d_out, int out_size, void* d_ws, size_t ws_size,
                              hipStream_t stream)
{
    const float* x    = (const float*)d_in[0];
    const float* c1w  = (const float*)d_in[1];
    const float* c1b  = (const float*)d_in[2];
    const float* g1   = (const float*)d_in[3];
    const float* b1   = (const float*)d_in[4];
    const float* c2w  = (const float*)d_in[5];
    const float* c2b  = (const float*)d_in[6];
    const float* g2   = (const float*)d_in[7];
    const float* b2   = (const float*)d_in[8];
    const float* pw   = (const float*)d_in[9];
    const float* pb   = (const float*)d_in[10];
    const float* g3   = (const float*)d_in[11];
    const float* b3   = (const float*)d_in[12];
    const float* ipw  = (const float*)d_in[13];
    const float* ipb  = (const float*)d_in[14];
    const float* cw   = (const float*)d_in[15];
    const float* cb   = (const float*)d_in[16];
    const float* xpw  = (const float*)d_in[17];
    const float* dpw  = (const float*)d_in[18];
    const float* dpb  = (const float*)d_in[19];
    const float* alog = (const float*)d_in[20];
    const float* dssm = (const float*)d_in[21];
    const float* opw  = (const float*)d_in[22];
    const float* opb  = (const float*)d_in[23];
    const float* lnw  = (const float*)d_in[24];
    const float* lnb  = (const float*)d_in[25];
    const float* nw   = (const float*)d_in[26];
    const float* nb   = (const float*)d_in[27];
    const float* fcw  = (const float*)d_in[28];
    const float* fcb  = (const float*)d_in[29];
    float* out = (float*)d_out;
    float* wsf = (float*)d_ws;

    // workspace layout (floats), lifetime-overlapped; total 11,928,576 fl = 47.7 MB
    float* s_    = wsf;              // [4096,256]      stem output / residual stream
    float* h1    = wsf + 1048576;    // [4,128,64,64]   conv1 out   (later: u)
    float* u_    = h1;               // [4,512,1024]    dwconv out, [b,d,l]
    float* h2    = wsf + 3145728;    // [4,256,64,64]   conv2 out   (later: xl / ybuf)
    float* xl    = h2;               // [4096,512]
    float* ybuf  = h2;               // [4096,512]      (xl dead before scan writes)
    float* delta = wsf + 5242880;    // [4,512,1024]    (later: obuf)
    float* obuf  = delta;            // [4096,256]      (delta dead before out_proj)
    float* Ap    = wsf + 7340032;    // [4096,1024]     patch im2col (later: xr)
    float* xr    = Ap;               // [4096,1024]
    float* xdbl  = wsf + 11534336;   // [4096,64]
    float* Btb   = wsf + 11796480;   // [4,16,1024]
    float* Ctb   = wsf + 11862016;   // [4,16,1024]
    float* sln   = wsf + 11927552;   // [4,256]

    // --- conv stem ---
    hipLaunchKernelGGL(conv3x3_bn_gelu, dim3(4 * 128, 4), dim3(256), 0, stream,
                       x, c1w, c1b, g1, b1, h1, 3, 128);
    hipLaunchKernelGGL(conv3x3_bn_gelu, dim3(4 * 256, 4), dim3(256), 0, stream,
                       h1, c2w, c2b, g2, b2, h2, 128, 256);
    hipLaunchKernelGGL(im2col_patch_kernel, dim3(64, 16), dim3(256), 0, stream, h2, Ap);
    hipLaunchKernelGGL((gemm_kernel<64, 64, 16, 4, 4>), dim3(64, 4), dim3(256), 0, stream,
                       Ap, 1024, pw, 1024, pb, g3, b3, s_, 256, 4096, 256, 1024, 1, 0);

    // --- mamba blocks ---
    for (int i = 0; i < 4; ++i) {
        const float* ipw_i  = ipw + (size_t)i * 1024 * 256;
        const float* ipb_i  = ipb + i * 1024;
        const float* cw_i   = cw + i * 512 * 4;
        const float* cb_i   = cb + i * 512;
        const float* xpw_i  = xpw + (size_t)i * 64 * 512;
        const float* dpw_i  = dpw + (size_t)i * 512 * 32;
        const float* dpb_i  = dpb + i * 512;
        const float* alog_i = alog + (size_t)i * 512 * 16;
        const float* dssm_i = dssm + i * 512;
        const float* opw_i  = opw + (size_t)i * 256 * 512;
        const float* opb_i  = opb + i * 256;
        const float* lnw_i  = lnw + i * 256;
        const float* lnb_i  = lnb + i * 256;

        // in_proj: xr[b,l,1024] = s @ ipw^T + ipb
        hipLaunchKernelGGL((gemm_kernel<128, 128, 8, 8, 8>), dim3(32, 8), dim3(256), 0, stream,
                           s_, 256, ipw_i, 256, ipb_i, nullptr, nullptr, xr, 1024,
                           4096, 1024, 256, 0, 0);
        hipLaunchKernelGGL(dwconv_dual, dim3(512), dim3(256), 0, stream, xr, cw_i, cb_i, xl, u_);
        // x_proj: xdbl[b,l,64] = xl @ xpw^T
        hipLaunchKernelGGL((gemm_kernel<64, 64, 16, 4, 4>), dim3(64, 1), dim3(256), 0, stream,
                           xl, 512, xpw_i, 512, nullptr, nullptr, nullptr, xdbl, 64,
                           4096, 64, 512, 0, 0);
        hipLaunchKernelGGL(tbc_kernel, dim3(256), dim3(256), 0, stream, xdbl, Btb, Ctb);
        // dt_proj + softplus, stored transposed as delta[b,d,l]
        hipLaunchKernelGGL((gemm_kernel<64, 64, 16, 4, 4>), dim3(64, 8), dim3(256), 0, stream,
                           xdbl, 64, dpw_i, 32, dpb_i, nullptr, nullptr, delta, 512,
                           4096, 512, 32, 2, 1);
        hipLaunchKernelGGL(scan_kernel, dim3(128), dim3(256), 0, stream,
                           delta, u_, Btb, Ctb, alog_i, dssm_i, ybuf);
        hipLaunchKernelGGL(gate_kernel, dim3(8192), dim3(256), 0, stream, ybuf, xr);
        // out_proj: obuf[b,l,256] = ybuf @ opw^T + opb
        hipLaunchKernelGGL((gemm_kernel<64, 64, 16, 4, 4>), dim3(64, 4), dim3(256), 0, stream,
                           ybuf, 512, opw_i, 512, opb_i, nullptr, nullptr, obuf, 256,
                           4096, 256, 512, 0, 0);
        hipLaunchKernelGGL(ln_res_kernel, dim3(1024), dim3(256), 0, stream,
                           obuf, lnw_i, lnb_i, s_);
    }

    // --- head ---
    hipLaunchKernelGGL(pool_ln_kernel, dim3(4), dim3(256), 0, stream, s_, nw, nb, sln);
    hipLaunchKernelGGL((gemm_kernel<64, 64, 16, 4, 4>), dim3(1, 16), dim3(256), 0, stream,
                       sln, 256, fcw, 256, fcb, nullptr, nullptr, out, 1000,
                       4, 1000, 256, 0, 0);
    hipLaunchKernelGGL(softmax_kernel, dim3(1), dim3(256), 0, stream, out);
}

// Round 2
// 1545.819 us; speedup vs baseline: 1.5685x; 1.5685x over previous
//
#include <hip/hip_runtime.h>
#include <math.h>

// ---------------------------------------------------------------------------
// FastImageMamba forward, fp32. R2: conv stem as NHWC implicit GEMM.
// B=4, DM=256, NL=4, NC=1000, DI=512, NS=16, DTR=32, K=4, L=1024 (32x32), H=W=64
// ---------------------------------------------------------------------------

#define BN_RSQ 0.99999500003749969f   // 1/sqrt(1+1e-5)

__device__ __forceinline__ float gelu_f(float v) {
    return 0.5f * v * (1.0f + erff(v * 0.70710678118654752f));
}
__device__ __forceinline__ float softplus_f(float v) {
    return (v > 20.f) ? v : log1pf(expf(v));
}

// ---------------------------------------------------------------------------
// conv1: 3x3 s1p1, IC=3 -> OC=128, NCHW input, NHWC output + bias+BN+GELU.
// One block per (b,y) row. Weights + 3 input rows staged in LDS.
// ---------------------------------------------------------------------------
__global__ __launch_bounds__(256) void conv1_nhwc(
    const float* __restrict__ x, const float* __restrict__ w,
    const float* __restrict__ cb, const float* __restrict__ g,
    const float* __restrict__ bb, float* __restrict__ out)
{
    __shared__ float tin[3][3][64];
    __shared__ float ws[3456];
    int t = threadIdx.x;
    int b = blockIdx.x >> 6, y = blockIdx.x & 63;
    for (int i = t; i < 3456; i += 256) ws[i] = w[i];
    for (int i = t; i < 576; i += 256) {
        int ic = i / 192, r = (i >> 6) % 3, xx = i & 63;
        int gy = y + r - 1;
        tin[ic][r][xx] = ((unsigned)gy < 64u) ? x[((b * 3 + ic) * 64 + gy) * 64 + xx] : 0.f;
    }
    __syncthreads();
    int tx = t & 15, ty = t >> 4;
    int oc0 = tx * 8, px0 = ty * 4;
    float acc[4][8];
    #pragma unroll
    for (int p = 0; p < 4; ++p)
        #pragma unroll
        for (int o = 0; o < 8; ++o) acc[p][o] = 0.f;
    for (int ic = 0; ic < 3; ++ic)
        #pragma unroll
        for (int ky = 0; ky < 3; ++ky)
            #pragma unroll
            for (int kx = 0; kx < 3; ++kx) {
                float av[4];
                #pragma unroll
                for (int p = 0; p < 4; ++p) {
                    int xx = px0 + p + kx - 1;
                    av[p] = ((unsigned)xx < 64u) ? tin[ic][ky][xx] : 0.f;
                }
                #pragma unroll
                for (int o = 0; o < 8; ++o) {
                    float wv = ws[(oc0 + o) * 27 + ic * 9 + ky * 3 + kx];
                    #pragma unroll
                    for (int p = 0; p < 4; ++p) acc[p][o] = fmaf(av[p], wv, acc[p][o]);
                }
            }
    #pragma unroll
    for (int p = 0; p < 4; ++p) {
        float o8[8];
        #pragma unroll
        for (int o = 0; o < 8; ++o) {
            int oc = oc0 + o;
            o8[o] = gelu_f((acc[p][o] + cb[oc]) * (g[oc] * BN_RSQ) + bb[oc]);
        }
        float* dst = out + ((size_t)((b * 64 + y) * 64 + px0 + p)) * 128 + oc0;
        *(float4*)dst = make_float4(o8[0], o8[1], o8[2], o8[3]);
        *(float4*)(dst + 4) = make_float4(o8[4], o8[5], o8[6], o8[7]);
    }
}

// w2[oc][s*128+ic] = c2w[oc][ic][ky][kx], s = ky*3+kx
__global__ void w2_kernel(const float* __restrict__ c2w, float* __restrict__ w2)
{
    int idx = blockIdx.x * 256 + threadIdx.x;          // 294912
    int oc = idx / 1152, k = idx % 1152;
    int s = k >> 7, ic = k & 127;
    w2[idx] = c2w[(size_t)(oc * 128 + ic) * 9 + s];
}

// ---------------------------------------------------------------------------
// conv2: 3x3 s1p1, IC=128 -> OC=256 as 9-shift implicit GEMM over NHWC.
// A: h1 NHWC [4,64,64,128]; W2: [256][1152]; out: h2 NHWC [4,64,64,256].
// Tile: 128 pixels (2 rows) x 64 oc, BK=32; 256 thr, micro 8x4. grid (128,4).
// ---------------------------------------------------------------------------
__global__ __launch_bounds__(256) void conv2_gemm(
    const float* __restrict__ A, const float* __restrict__ W2,
    const float* __restrict__ cb, const float* __restrict__ g,
    const float* __restrict__ bb, float* __restrict__ out)
{
    __shared__ float As[32][132];
    __shared__ float Bs[32][68];
    int t = threadIdx.x;
    int m0 = blockIdx.x * 128;
    int n0 = blockIdx.y * 64;
    int b = m0 >> 12;
    int y0 = (m0 & 4095) >> 6;
    int ty = t >> 4, tx = t & 15;
    int apx = t >> 1;                 // pixel 0..127 within tile
    int aicq = (t & 1) * 16;          // ic sub-offset 0 / 16
    int ay = y0 + (apx >> 6);
    int ax = apx & 63;
    int boc = t >> 2;                 // 0..63
    int bicq = (t & 3) * 8;           // 0,8,16,24
    float acc[8][4];
    #pragma unroll
    for (int i = 0; i < 8; ++i)
        #pragma unroll
        for (int j = 0; j < 4; ++j) acc[i][j] = 0.f;

    for (int s = 0; s < 9; ++s) {
        int ky = s / 3, kx = s % 3;
        int sy = ay + ky - 1, sx = ax + kx - 1;
        bool aval = ((unsigned)sy < 64u) && ((unsigned)sx < 64u);
        const float* ap = A + (((size_t)(b * 64 + sy)) * 64 + sx) * 128 + aicq;
        const float* wp = W2 + (size_t)(n0 + boc) * 1152 + s * 128 + bicq;
        for (int ic0 = 0; ic0 < 128; ic0 += 32) {
            float4 va[4];
            #pragma unroll
            for (int q = 0; q < 4; ++q)
                va[q] = aval ? *(const float4*)(ap + ic0 + q * 4)
                             : make_float4(0.f, 0.f, 0.f, 0.f);
            float4 vb0 = *(const float4*)(wp + ic0);
            float4 vb1 = *(const float4*)(wp + ic0 + 4);
            __syncthreads();
            #pragma unroll
            for (int q = 0; q < 4; ++q) {
                As[aicq + q * 4 + 0][apx] = va[q].x;
                As[aicq + q * 4 + 1][apx] = va[q].y;
                As[aicq + q * 4 + 2][apx] = va[q].z;
                As[aicq + q * 4 + 3][apx] = va[q].w;
            }
            Bs[bicq + 0][boc] = vb0.x; Bs[bicq + 1][boc] = vb0.y;
            Bs[bicq + 2][boc] = vb0.z; Bs[bicq + 3][boc] = vb0.w;
            Bs[bicq + 4][boc] = vb1.x; Bs[bicq + 5][boc] = vb1.y;
            Bs[bicq + 6][boc] = vb1.z; Bs[bicq + 7][boc] = vb1.w;
            __syncthreads();
            #pragma unroll
            for (int kk = 0; kk < 32; ++kk) {
                float a8[8], b4[4];
                *(float4*)&a8[0] = *(const float4*)&As[kk][ty * 8];
                *(float4*)&a8[4] = *(const float4*)&As[kk][ty * 8 + 4];
                *(float4*)&b4[0] = *(const float4*)&Bs[kk][tx * 4];
                #pragma unroll
                for (int i = 0; i < 8; ++i)
                    #pragma unroll
                    for (int j = 0; j < 4; ++j)
                        acc[i][j] = fmaf(a8[i], b4[j], acc[i][j]);
            }
        }
    }
    float sc[4], sh[4], cbv[4];
    #pragma unroll
    for (int j = 0; j < 4; ++j) {
        int n = n0 + tx * 4 + j;
        sc[j] = g[n] * BN_RSQ; sh[j] = bb[n]; cbv[j] = cb[n];
    }
    #pragma unroll
    for (int i = 0; i < 8; ++i) {
        int m = m0 + ty * 8 + i;
        float4 o;
        o.x = gelu_f((acc[i][0] + cbv[0]) * sc[0] + sh[0]);
        o.y = gelu_f((acc[i][1] + cbv[1]) * sc[1] + sh[1]);
        o.z = gelu_f((acc[i][2] + cbv[2]) * sc[2] + sh[2]);
        o.w = gelu_f((acc[i][3] + cbv[3]) * sc[3] + sh[3]);
        *(float4*)(out + (size_t)m * 256 + n0 + tx * 4) = o;
    }
}

// pwT[oc][s*256+ic] = pw[oc][ic][ky][kx], s = ky*2+kx
__global__ void pwT_kernel(const float* __restrict__ pw, float* __restrict__ pwT)
{
    int idx = blockIdx.x * 256 + threadIdx.x;          // 262144
    int oc = idx >> 10, k = idx & 1023;
    int s = k >> 8, ic = k & 255;
    int ky = s >> 1, kx = s & 1;
    pwT[idx] = pw[((size_t)(oc * 256 + ic) * 2 + ky) * 2 + kx];
}

// Ap[m][s*256+ic] = h2nhwc[b, 2oy+ky, 2ox+kx, ic]  (fully coalesced both sides)
__global__ void im2col_patch_nhwc(const float* __restrict__ h2, float* __restrict__ Ap)
{
    int idx = blockIdx.x * 256 + threadIdx.x;          // 1,048,576 float4s
    int k4 = idx & 255;                                // k/4
    int m = idx >> 8;
    int b = m >> 10, oy = (m >> 5) & 31, ox = m & 31;
    int s = k4 >> 6;
    int ky = s >> 1, kx = s & 1;
    float4 v = *(const float4*)(h2 + ((size_t)(b * 4096 + (2 * oy + ky) * 64 + 2 * ox + kx)) * 256
                                + (k4 & 63) * 4);
    ((float4*)Ap)[idx] = v;
}

// ---------------------------------------------------------------------------
// Generic tiled fp32 GEMM: C[M,N] = act( bn( A[M,K] @ W[N,K]^T + bias ) )
// act: 0 none, 1 gelu, 2 softplus. bn applied iff bnG != null.
// smode: 0 -> C[m*ldc+n]; 1 -> delta store C[(b*N+n)*1024 + l], m=b*1024+l.
// ---------------------------------------------------------------------------
template<int BM, int BN, int BK, int TM, int TN>
__global__ __launch_bounds__(256) void gemm_kernel(
    const float* __restrict__ A, int lda,
    const float* __restrict__ W, int ldw,
    const float* __restrict__ bias,
    const float* __restrict__ bnG, const float* __restrict__ bnB,
    float* __restrict__ C, int ldc,
    int M, int N, int K, int act, int smode)
{
    static_assert(BM * BK / 4 == 256 && BN * BK / 4 == 256, "staging shape");
    __shared__ float As[BK][BM + 4];
    __shared__ float Bs[BK][BN + 4];
    int t = threadIdx.x;
    int m0 = blockIdx.x * BM, n0 = blockIdx.y * BN;
    float acc[TM][TN];
    #pragma unroll
    for (int i = 0; i < TM; i++)
        #pragma unroll
        for (int j = 0; j < TN; j++) acc[i][j] = 0.f;
    const int LPR = BK / 4;
    int lr = t / LPR, lc4 = (t % LPR) * 4;
    int ty = t >> 4, tx = t & 15;
    for (int k0 = 0; k0 < K; k0 += BK) {
        float4 va = make_float4(0.f, 0.f, 0.f, 0.f);
        float4 vb = make_float4(0.f, 0.f, 0.f, 0.f);
        int ma = m0 + lr;
        if (ma < M) va = *(const float4*)(A + (size_t)ma * lda + k0 + lc4);
        int nb = n0 + lr;
        if (nb < N) vb = *(const float4*)(W + (size_t)nb * ldw + k0 + lc4);
        __syncthreads();
        As[lc4 + 0][lr] = va.x; As[lc4 + 1][lr] = va.y;
        As[lc4 + 2][lr] = va.z; As[lc4 + 3][lr] = va.w;
        Bs[lc4 + 0][lr] = vb.x; Bs[lc4 + 1][lr] = vb.y;
        Bs[lc4 + 2][lr] = vb.z; Bs[lc4 + 3][lr] = vb.w;
        __syncthreads();
        #pragma unroll
        for (int kk = 0; kk < BK; ++kk) {
            float a[TM], bfr[TN];
            #pragma unroll
            for (int i = 0; i < TM; i += 4)
                *(float4*)&a[i] = *(const float4*)&As[kk][ty * TM + i];
            #pragma unroll
            for (int j = 0; j < TN; j += 4)
                *(float4*)&bfr[j] = *(const float4*)&Bs[kk][tx * TN + j];
            #pragma unroll
            for (int i = 0; i < TM; i++)
                #pragma unroll
                for (int j = 0; j < TN; j++) acc[i][j] = fmaf(a[i], bfr[j], acc[i][j]);
        }
    }
    #pragma unroll
    for (int i = 0; i < TM; i++) {
        int m = m0 + ty * TM + i;
        if (m >= M) continue;
        int bI = m >> 10, lI = m & 1023;
        #pragma unroll
        for (int j = 0; j < TN; j++) {
            int n = n0 + tx * TN + j;
            if (n >= N) continue;
            float v = acc[i][j];
            if (bias) v += bias[n];
            if (bnG)  v = v * (bnG[n] * BN_RSQ) + bnB[n];
            if (act == 1) v = gelu_f(v);
            else if (act == 2) v = softplus_f(v);
            if (smode == 0) C[(size_t)m * ldc + n] = v;
            else            C[((size_t)(bI * N + n) << 10) + lI] = v;
        }
    }
}

// ---------------------------------------------------------------------------
// Depthwise conv1d (K=4, pad(1,2)) on xi = xr[:, :, 0:512]; dual-layout store.
// ---------------------------------------------------------------------------
__global__ __launch_bounds__(256) void dwconv_dual(
    const float* __restrict__ xr, const float* __restrict__ cw,
    const float* __restrict__ cb, float* __restrict__ xl, float* __restrict__ u)
{
    __shared__ float tin[68][65];
    __shared__ float tout[64][65];
    int t = threadIdx.x;
    int bid = blockIdx.x;
    int dt_ = bid & 7, lt = (bid >> 3) & 15, b = bid >> 7;
    int d0 = dt_ * 64, l0 = lt * 64;
    int lane = t & 63, grp = t >> 6;
    for (int r = grp; r < 68; r += 4) {
        int l = l0 + r - 1;
        float v = 0.f;
        if ((unsigned)l < 1024u) v = xr[(size_t)(b * 1024 + l) * 1024 + d0 + lane];
        tin[r][lane] = v;
    }
    __syncthreads();
    {
        int d = d0 + lane;
        float w0 = cw[d * 4 + 0], w1 = cw[d * 4 + 1], w2 = cw[d * 4 + 2], w3 = cw[d * 4 + 3];
        float bv = cb[d];
        int li0 = grp * 16;
        #pragma unroll
        for (int q = 0; q < 16; ++q) {
            int li = li0 + q;
            float v = bv + w0 * tin[li][lane] + w1 * tin[li + 1][lane]
                         + w2 * tin[li + 2][lane] + w3 * tin[li + 3][lane];
            tout[li][lane] = v;
        }
    }
    __syncthreads();
    for (int r = grp; r < 64; r += 4)
        xl[(size_t)(b * 1024 + l0 + r) * 512 + d0 + lane] = tout[r][lane];
    for (int r = grp; r < 64; r += 4)
        u[(size_t)(b * 512 + d0 + r) * 1024 + l0 + lane] = tout[lane][r];
}

// Transpose B/C slices of xdbl[b,l,64] -> Bt/Ct [b,16,1024]
__global__ void tbc_kernel(const float* __restrict__ xdbl,
                           float* __restrict__ Bt, float* __restrict__ Ct)
{
    int idx = blockIdx.x * 256 + threadIdx.x;   // 65536
    int l = idx & 1023, r = idx >> 10;
    int n = r & 15, b = r >> 4;
    const float* src = xdbl + (size_t)((b << 10) + l) * 64;
    Bt[idx] = src[32 + n];
    Ct[idx] = src[48 + n];
}

// ---------------------------------------------------------------------------
// Selective scan. One wave per (b, 4 d's); lane = dl*16 + n; shfl-reduce over n.
// ---------------------------------------------------------------------------
__global__ __launch_bounds__(256) void scan_kernel(
    const float* __restrict__ delta, const float* __restrict__ u,
    const float* __restrict__ Bt, const float* __restrict__ Ct,
    const float* __restrict__ alog, const float* __restrict__ dssm,
    float* __restrict__ y)
{
    int wid = (blockIdx.x * 256 + threadIdx.x) >> 6;
    int lane = threadIdx.x & 63;
    int b = wid >> 7, dg = wid & 127;
    int dl = lane >> 4, n = lane & 15;
    int d = dg * 4 + dl;
    float Ac = -__expf(alog[d * 16 + n]);
    float Dd = dssm[d];
    const float4* dp = (const float4*)(delta + ((size_t)(b * 512 + d) << 10));
    const float4* up = (const float4*)(u + ((size_t)(b * 512 + d) << 10));
    const float4* Bp = (const float4*)(Bt + ((size_t)(b * 16 + n) << 10));
    const float4* Cp = (const float4*)(Ct + ((size_t)(b * 16 + n) << 10));
    float* yp = y + ((size_t)b << 19) + d;
    float h = 0.f;
    float4 de = dp[0], uu = up[0], Bv = Bp[0], Cv = Cp[0];
    for (int it = 0; it < 256; ++it) {
        int nx = (it < 255) ? it + 1 : 255;
        float4 de2 = dp[nx], uu2 = up[nx], Bv2 = Bp[nx], Cv2 = Cp[nx];
        float p0, p1, p2, p3;
        h = __expf(de.x * Ac) * h + de.x * Bv.x * uu.x; p0 = h * Cv.x;
        h = __expf(de.y * Ac) * h + de.y * Bv.y * uu.y; p1 = h * Cv.y;
        h = __expf(de.z * Ac) * h + de.z * Bv.z * uu.z; p2 = h * Cv.z;
        h = __expf(de.w * Ac) * h + de.w * Bv.w * uu.w; p3 = h * Cv.w;
        #pragma unroll
        for (int off = 1; off < 16; off <<= 1) {
            p0 += __shfl_xor(p0, off);
            p1 += __shfl_xor(p1, off);
            p2 += __shfl_xor(p2, off);
            p3 += __shfl_xor(p3, off);
        }
        if (n == 0) {
            size_t l = (size_t)it * 4;
            yp[(l + 0) * 512] = p0 + uu.x * Dd;
            yp[(l + 1) * 512] = p1 + uu.y * Dd;
            yp[(l + 2) * 512] = p2 + uu.z * Dd;
            yp[(l + 3) * 512] = p3 + uu.w * Dd;
        }
        de = de2; uu = uu2; Bv = Bv2; Cv = Cv2;
    }
}

// y[b,l,d] *= silu(res), res = xr[b,l,512+d]
__global__ void gate_kernel(float* __restrict__ y, const float* __restrict__ xr)
{
    int idx = blockIdx.x * 256 + threadIdx.x;   // 2,097,152
    int d = idx & 511;
    int bl = idx >> 9;
    float r = xr[(size_t)bl * 1024 + 512 + d];
    float s = r / (1.f + __expf(-r));
    y[idx] *= s;
}

// s[row] = LN(o[row])*g + b + s[row]; one wave per 256-elem row
__global__ __launch_bounds__(256) void ln_res_kernel(
    const float* __restrict__ o, const float* __restrict__ g,
    const float* __restrict__ bb, float* __restrict__ s)
{
    int row = blockIdx.x * 4 + (threadIdx.x >> 6);
    int lane = threadIdx.x & 63;
    const float4* orow = (const float4*)(o + (size_t)row * 256);
    float4 v = orow[lane];
    float sum = v.x + v.y + v.z + v.w;
    float sq = v.x * v.x + v.y * v.y + v.z * v.z + v.w * v.w;
    #pragma unroll
    for (int off = 1; off < 64; off <<= 1) {
        sum += __shfl_xor(sum, off);
        sq += __shfl_xor(sq, off);
    }
    float m = sum * (1.f / 256.f);
    float var = sq * (1.f / 256.f) - m * m;
    float rstd = rsqrtf(var + 1e-5f);
    float4 gg = ((const float4*)g)[lane];
    float4 bv = ((const float4*)bb)[lane];
    float4* srow = (float4*)(s + (size_t)row * 256);
    float4 sv = srow[lane];
    sv.x += (v.x - m) * rstd * gg.x + bv.x;
    sv.y += (v.y - m) * rstd * gg.y + bv.y;
    sv.z += (v.z - m) * rstd * gg.z + bv.z;
    sv.w += (v.w - m) * rstd * gg.w + bv.w;
    srow[lane] = sv;
}

// mean over l (1024) then LN over 256 channels. grid 4 x 256.
__global__ __launch_bounds__(256) void pool_ln_kernel(
    const float* __restrict__ s, const float* __restrict__ nw,
    const float* __restrict__ nb, float* __restrict__ sln)
{
    int b = blockIdx.x, c = threadIdx.x;
    const float* p = s + (size_t)b * 262144 + c;
    float acc = 0.f;
    for (int l = 0; l < 1024; ++l) acc += p[(size_t)l * 256];
    float pooled = acc * (1.f / 1024.f);
    __shared__ float rs[4], rq[4];
    float sum = pooled, sq = pooled * pooled;
    #pragma unroll
    for (int off = 1; off < 64; off <<= 1) {
        sum += __shfl_xor(sum, off);
        sq += __shfl_xor(sq, off);
    }
    int w = threadIdx.x >> 6;
    if ((threadIdx.x & 63) == 0) { rs[w] = sum; rq[w] = sq; }
    __syncthreads();
    sum = rs[0] + rs[1] + rs[2] + rs[3];
    sq = rq[0] + rq[1] + rq[2] + rq[3];
    float m = sum * (1.f / 256.f);
    float var = sq * (1.f / 256.f) - m * m;
    float rstd = rsqrtf(var + 1e-5f);
    sln[b * 256 + c] = (pooled - m) * rstd * nw[c] + nb[c];
}

// softmax over 1000 logits per b
__global__ __launch_bounds__(256) void softmax_kernel(float* __restrict__ out)
{
    int b = threadIdx.x >> 6, lane = threadIdx.x & 63;
    const float* lg = out + b * 1000;
    float v[16];
    float mx = -1e30f;
    #pragma unroll
    for (int j = 0; j < 16; ++j) {
        int i = lane + j * 64;
        v[j] = (i < 1000) ? lg[i] : -1e30f;
        mx = fmaxf(mx, v[j]);
    }
    #pragma unroll
    for (int off = 1; off < 64; off <<= 1) mx = fmaxf(mx, __shfl_xor(mx, off));
    float sum = 0.f;
    #pragma unroll
    for (int j = 0; j < 16; ++j) {
        int i = lane + j * 64;
        if (i < 1000) { v[j] = __expf(v[j] - mx); sum += v[j]; }
    }
    #pragma unroll
    for (int off = 1; off < 64; off <<= 1) sum += __shfl_xor(sum, off);
    float inv = 1.f / sum;
    float* so = out + 4000 + b * 1000;
    #pragma unroll
    for (int j = 0; j < 16; ++j) {
        int i = lane + j * 64;
        if (i < 1000) so[i] = v[j] * inv;
    }
}

// ---------------------------------------------------------------------------
extern "C" void kernel_launch(void* const* d_in, const int* in_sizes, int n_in,
                              void* d_out, int out_size, void* d_ws, size_t ws_size,
                              hipStream_t stream)
{
    const float* x    = (const float*)d_in[0];
    const float* c1w  = (const float*)d_in[1];
    const float* c1b  = (const float*)d_in[2];
    const float* g1   = (const float*)d_in[3];
    const float* b1   = (const float*)d_in[4];
    const float* c2w  = (const float*)d_in[5];
    const float* c2b  = (const float*)d_in[6];
    const float* g2   = (const float*)d_in[7];
    const float* b2   = (const float*)d_in[8];
    const float* pw   = (const float*)d_in[9];
    const float* pb   = (const float*)d_in[10];
    const float* g3   = (const float*)d_in[11];
    const float* b3   = (const float*)d_in[12];
    const float* ipw  = (const float*)d_in[13];
    const float* ipb  = (const float*)d_in[14];
    const float* cw   = (const float*)d_in[15];
    const float* cb   = (const float*)d_in[16];
    const float* xpw  = (const float*)d_in[17];
    const float* dpw  = (const float*)d_in[18];
    const float* dpb  = (const float*)d_in[19];
    const float* alog = (const float*)d_in[20];
    const float* dssm = (const float*)d_in[21];
    const float* opw  = (const float*)d_in[22];
    const float* opb  = (const float*)d_in[23];
    const float* lnw  = (const float*)d_in[24];
    const float* lnb  = (const float*)d_in[25];
    const float* nw   = (const float*)d_in[26];
    const float* nb   = (const float*)d_in[27];
    const float* fcw  = (const float*)d_in[28];
    const float* fcb  = (const float*)d_in[29];
    float* out = (float*)d_out;
    float* wsf = (float*)d_ws;

    // workspace layout (floats), lifetime-overlapped; total ~45.5 MB
    float* s_    = wsf;              // [4096,256]  residual stream (stem-time: w2 scratch)
    float* h1    = wsf + 1048576;    // [4,64,64,128] NHWC conv1 out (later: u)
    float* u_    = h1;               // [4,512,1024]
    float* h2    = wsf + 3145728;    // [4,64,64,256] NHWC conv2 out (4M fl, spans xl+delta regions; dead before those are written)
    float* xl    = h2;               // [4096,512]
    float* ybuf  = h2;               // [4096,512]
    float* delta = wsf + 5242880;    // [4,512,1024] (later: obuf)
    float* obuf  = delta;            // [4096,256]
    float* Ap    = wsf + 7340032;    // [4096,1024]  patch im2col (later: xr)
    float* xr    = Ap;               // [4096,1024]
    float* xdbl  = wsf + 11534336;   // [4096,64]    (stem-time: pwT scratch, 262144 fl exactly)
    float* Btb   = wsf + 11796480;   // [4,16,1024]
    float* Ctb   = wsf + 11862016;   // [4,16,1024]
    float* sln   = wsf + 11927552;   // [4,256]
    float* w2    = s_;               // [256,1152] conv2 weights re-laid (dead before s_ written)
    float* pwT   = xdbl;             // [256,1024] patch weights re-laid (dead before xdbl written)

    // --- conv stem ---
    hipLaunchKernelGGL(w2_kernel, dim3(1152), dim3(256), 0, stream, c2w, w2);
    hipLaunchKernelGGL(pwT_kernel, dim3(1024), dim3(256), 0, stream, pw, pwT);
    hipLaunchKernelGGL(conv1_nhwc, dim3(256), dim3(256), 0, stream, x, c1w, c1b, g1, b1, h1);
    hipLaunchKernelGGL(conv2_gemm, dim3(128, 4), dim3(256), 0, stream, h1, w2, c2b, g2, b2, h2);
    hipLaunchKernelGGL(im2col_patch_nhwc, dim3(4096), dim3(256), 0, stream, h2, Ap);
    hipLaunchKernelGGL((gemm_kernel<64, 64, 16, 4, 4>), dim3(64, 4), dim3(256), 0, stream,
                       Ap, 1024, pwT, 1024, pb, g3, b3, s_, 256, 4096, 256, 1024, 1, 0);

    // --- mamba blocks ---
    for (int i = 0; i < 4; ++i) {
        const float* ipw_i  = ipw + (size_t)i * 1024 * 256;
        const float* ipb_i  = ipb + i * 1024;
        const float* cw_i   = cw + i * 512 * 4;
        const float* cb_i   = cb + i * 512;
        const float* xpw_i  = xpw + (size_t)i * 64 * 512;
        const float* dpw_i  = dpw + (size_t)i * 512 * 32;
        const float* dpb_i  = dpb + i * 512;
        const float* alog_i = alog + (size_t)i * 512 * 16;
        const float* dssm_i = dssm + i * 512;
        const float* opw_i  = opw + (size_t)i * 256 * 512;
        const float* opb_i  = opb + i * 256;
        const float* lnw_i  = lnw + i * 256;
        const float* lnb_i  = lnb + i * 256;

        hipLaunchKernelGGL((gemm_kernel<128, 128, 8, 8, 8>), dim3(32, 8), dim3(256), 0, stream,
                           s_, 256, ipw_i, 256, ipb_i, nullptr, nullptr, xr, 1024,
                           4096, 1024, 256, 0, 0);
        hipLaunchKernelGGL(dwconv_dual, dim3(512), dim3(256), 0, stream, xr, cw_i, cb_i, xl, u_);
        hipLaunchKernelGGL((gemm_kernel<64, 64, 16, 4, 4>), dim3(64, 1), dim3(256), 0, stream,
                           xl, 512, xpw_i, 512, nullptr, nullptr, nullptr, xdbl, 64,
                           4096, 64, 512, 0, 0);
        hipLaunchKernelGGL(tbc_kernel, dim3(256), dim3(256), 0, stream, xdbl, Btb, Ctb);
        hipLaunchKernelGGL((gemm_kernel<64, 64, 16, 4, 4>), dim3(64, 8), dim3(256), 0, stream,
                           xdbl, 64, dpw_i, 32, dpb_i, nullptr, nullptr, delta, 512,
                           4096, 512, 32, 2, 1);
        hipLaunchKernelGGL(scan_kernel, dim3(128), dim3(256), 0, stream,
                           delta, u_, Btb, Ctb, alog_i, dssm_i, ybuf);
        hipLaunchKernelGGL(gate_kernel, dim3(8192), dim3(256), 0, stream, ybuf, xr);
        hipLaunchKernelGGL((gemm_kernel<64, 64, 16, 4, 4>), dim3(64, 4), dim3(256), 0, stream,
                           ybuf, 512, opw_i, 512, opb_i, nullptr, nullptr, obuf, 256,
                           4096, 256, 512, 0, 0);
        hipLaunchKernelGGL(ln_res_kernel, dim3(1024), dim3(256), 0, stream,
                           obuf, lnw_i, lnb_i, s_);
    }

    // --- head ---
    hipLaunchKernelGGL(pool_ln_kernel, dim3(4), dim3(256), 0, stream, s_, nw, nb, sln);
    hipLaunchKernelGGL((gemm_kernel<64, 64, 16, 4, 4>), dim3(1, 16), dim3(256), 0, stream,
                       sln, 256, fcw, 256, fcb, nullptr, nullptr, out, 1000,
                       4, 1000, 256, 0, 0);
    hipLaunchKernelGGL(softmax_kernel, dim3(1), dim3(256), 0, stream, out);
}

// Round 4
// 1386.546 us; speedup vs baseline: 1.7487x; 1.1149x over previous
//
#include <hip/hip_runtime.h>
#include <math.h>

// ---------------------------------------------------------------------------
// FastImageMamba forward. R4: R3 (bf16 MFMA big GEMMs) + fixed workspace
// layout (R3's resb/u_ overlap caused NaN).
// B=4, DM=256, NL=4, NC=1000, DI=512, NS=16, DTR=32, K=4, L=1024, H=W=64
// ---------------------------------------------------------------------------

#define BN_RSQ 0.99999500003749969f   // 1/sqrt(1+1e-5)

typedef unsigned int uint;
typedef unsigned short ushort;
typedef __bf16 bf16x8 __attribute__((ext_vector_type(8)));
typedef float floatx4 __attribute__((ext_vector_type(4)));

__device__ __forceinline__ float gelu_f(float v) {
    return 0.5f * v * (1.0f + erff(v * 0.70710678118654752f));
}
__device__ __forceinline__ float softplus_f(float v) {
    return (v > 20.f) ? v : log1pf(expf(v));
}
__device__ __forceinline__ ushort f2bf(float f) {
    uint x = __float_as_uint(f);
    x += 0x7fffu + ((x >> 16) & 1u);
    return (ushort)(x >> 16);
}
__device__ __forceinline__ float bf2f(ushort u) {
    return __uint_as_float((uint)u << 16);
}

// float -> bf16 elementwise
__global__ void cvt_bf16(const float* __restrict__ src, ushort* __restrict__ dst, int n)
{
    int i = blockIdx.x * 256 + threadIdx.x;
    if (i < n) dst[i] = f2bf(src[i]);
}

// w2b[oc][s*128+ic] = bf16(c2w[oc][ic][ky][kx]), s=ky*3+kx
__global__ void w2b_kernel(const float* __restrict__ c2w, ushort* __restrict__ w2b)
{
    int idx = blockIdx.x * 256 + threadIdx.x;          // 294912
    int oc = idx / 1152, k = idx % 1152;
    int s = k >> 7, ic = k & 127;
    w2b[idx] = f2bf(c2w[(size_t)(oc * 128 + ic) * 9 + s]);
}

// pwTb[oc][s*256+ic] = bf16(pw[oc][ic][ky][kx]), s=ky*2+kx
__global__ void pwTb_kernel(const float* __restrict__ pw, ushort* __restrict__ pwTb)
{
    int idx = blockIdx.x * 256 + threadIdx.x;          // 262144
    int oc = idx >> 10, k = idx & 1023;
    int s = k >> 8, ic = k & 255;
    int ky = s >> 1, kx = s & 1;
    pwTb[idx] = f2bf(pw[((size_t)(oc * 256 + ic) * 2 + ky) * 2 + kx]);
}

// ---------------------------------------------------------------------------
// conv1: 3x3 s1p1, IC=3 -> OC=128, NCHW fp32 in, NHWC bf16 out (+bias+BN+GELU)
// ---------------------------------------------------------------------------
__global__ __launch_bounds__(256) void conv1_nhwc(
    const float* __restrict__ x, const float* __restrict__ w,
    const float* __restrict__ cb, const float* __restrict__ g,
    const float* __restrict__ bb, ushort* __restrict__ out)
{
    __shared__ float tin[3][3][64];
    __shared__ float ws[3456];
    int t = threadIdx.x;
    int b = blockIdx.x >> 6, y = blockIdx.x & 63;
    for (int i = t; i < 3456; i += 256) ws[i] = w[i];
    for (int i = t; i < 576; i += 256) {
        int ic = i / 192, r = (i >> 6) % 3, xx = i & 63;
        int gy = y + r - 1;
        tin[ic][r][xx] = ((unsigned)gy < 64u) ? x[((b * 3 + ic) * 64 + gy) * 64 + xx] : 0.f;
    }
    __syncthreads();
    int tx = t & 15, ty = t >> 4;
    int oc0 = tx * 8, px0 = ty * 4;
    float acc[4][8];
    #pragma unroll
    for (int p = 0; p < 4; ++p)
        #pragma unroll
        for (int o = 0; o < 8; ++o) acc[p][o] = 0.f;
    for (int ic = 0; ic < 3; ++ic)
        #pragma unroll
        for (int ky = 0; ky < 3; ++ky)
            #pragma unroll
            for (int kx = 0; kx < 3; ++kx) {
                float av[4];
                #pragma unroll
                for (int p = 0; p < 4; ++p) {
                    int xx = px0 + p + kx - 1;
                    av[p] = ((unsigned)xx < 64u) ? tin[ic][ky][xx] : 0.f;
                }
                #pragma unroll
                for (int o = 0; o < 8; ++o) {
                    float wv = ws[(oc0 + o) * 27 + ic * 9 + ky * 3 + kx];
                    #pragma unroll
                    for (int p = 0; p < 4; ++p) acc[p][o] = fmaf(av[p], wv, acc[p][o]);
                }
            }
    #pragma unroll
    for (int p = 0; p < 4; ++p) {
        uint pk[4];
        #pragma unroll
        for (int o2 = 0; o2 < 4; ++o2) {
            int oc = oc0 + o2 * 2;
            float v0 = gelu_f((acc[p][o2 * 2] + cb[oc]) * (g[oc] * BN_RSQ) + bb[oc]);
            float v1 = gelu_f((acc[p][o2 * 2 + 1] + cb[oc + 1]) * (g[oc + 1] * BN_RSQ) + bb[oc + 1]);
            pk[o2] = (uint)f2bf(v0) | ((uint)f2bf(v1) << 16);
        }
        uint4 vv = make_uint4(pk[0], pk[1], pk[2], pk[3]);
        *(uint4*)(out + ((size_t)((b * 64 + y) * 64 + px0 + p)) * 128 + oc0) = vv;
    }
}

// ---------------------------------------------------------------------------
// Generic bf16 MFMA GEMM (A @ W^T), 128x128 tile, BK=32, 4 waves.
// EPI: 0 = +bias -> fp32 Cf[ldc]
//      1 = +bias,BN,GELU -> bf16 Cb[ldc]
//      2 = +bias,BN,GELU -> fp32 Cf + bf16 Cb (same ldc)
//      3 = in_proj: n<512 -> fp32 Cf[m*512+n]; n>=512 -> bf16 silu -> Cb[m*512+n-512]
// ---------------------------------------------------------------------------
template<int EPI>
__global__ __launch_bounds__(256) void mfma_gemm_bt(
    const ushort* __restrict__ A, int lda,
    const ushort* __restrict__ W, int ldw,
    const float* __restrict__ bias,
    const float* __restrict__ bnG, const float* __restrict__ bnB,
    float* __restrict__ Cf, ushort* __restrict__ Cb, int ldc, int K)
{
    __shared__ __align__(16) ushort As[128 * 40];
    __shared__ __align__(16) ushort Bs[128 * 40];
    int t = threadIdx.x;
    int m0 = blockIdx.x * 128, n0 = blockIdx.y * 128;
    int lane = t & 63;
    int wm = ((t >> 6) & 1) * 64, wn = (t >> 7) * 64;
    int fr = lane & 15, fk = (lane >> 4) * 8;
    int r0 = t >> 2, c0 = (t & 3) * 8;
    floatx4 acc[4][4];
    #pragma unroll
    for (int i = 0; i < 4; ++i)
        #pragma unroll
        for (int j = 0; j < 4; ++j) acc[i][j] = {0.f, 0.f, 0.f, 0.f};
    const ushort* Ap0 = A + (size_t)(m0 + r0) * lda + c0;
    const ushort* Ap1 = A + (size_t)(m0 + r0 + 64) * lda + c0;
    const ushort* Wp0 = W + (size_t)(n0 + r0) * ldw + c0;
    const ushort* Wp1 = W + (size_t)(n0 + r0 + 64) * ldw + c0;
    for (int k0 = 0; k0 < K; k0 += 32) {
        uint4 a0v = *(const uint4*)(Ap0 + k0);
        uint4 a1v = *(const uint4*)(Ap1 + k0);
        uint4 b0v = *(const uint4*)(Wp0 + k0);
        uint4 b1v = *(const uint4*)(Wp1 + k0);
        __syncthreads();
        *(uint4*)&As[r0 * 40 + c0] = a0v;
        *(uint4*)&As[(r0 + 64) * 40 + c0] = a1v;
        *(uint4*)&Bs[r0 * 40 + c0] = b0v;
        *(uint4*)&Bs[(r0 + 64) * 40 + c0] = b1v;
        __syncthreads();
        bf16x8 af[4], bw[4];
        #pragma unroll
        for (int i = 0; i < 4; ++i)
            af[i] = *(const bf16x8*)&As[(wm + i * 16 + fr) * 40 + fk];
        #pragma unroll
        for (int j = 0; j < 4; ++j)
            bw[j] = *(const bf16x8*)&Bs[(wn + j * 16 + fr) * 40 + fk];
        #pragma unroll
        for (int i = 0; i < 4; ++i)
            #pragma unroll
            for (int j = 0; j < 4; ++j)
                acc[i][j] = __builtin_amdgcn_mfma_f32_16x16x32_bf16(af[i], bw[j], acc[i][j], 0, 0, 0);
    }
    int rbase = (lane >> 4) * 4, cc = lane & 15;
    #pragma unroll
    for (int j = 0; j < 4; ++j) {
        int n = n0 + wn + j * 16 + cc;
        float bv = bias ? bias[n] : 0.f;
        float scl = 0.f, shf = 0.f;
        if (EPI == 1 || EPI == 2) { scl = bnG[n] * BN_RSQ; shf = bnB[n]; }
        #pragma unroll
        for (int i = 0; i < 4; ++i) {
            #pragma unroll
            for (int r = 0; r < 4; ++r) {
                int m = m0 + wm + i * 16 + rbase + r;
                float v = acc[i][j][r] + bv;
                if (EPI == 1 || EPI == 2) v = gelu_f(v * scl + shf);
                if (EPI == 0) {
                    Cf[(size_t)m * ldc + n] = v;
                } else if (EPI == 1) {
                    Cb[(size_t)m * ldc + n] = f2bf(v);
                } else if (EPI == 2) {
                    Cf[(size_t)m * ldc + n] = v;
                    Cb[(size_t)m * ldc + n] = f2bf(v);
                } else {
                    if (n < 512) Cf[(size_t)m * 512 + n] = v;
                    else Cb[(size_t)m * 512 + (n - 512)] = f2bf(v / (1.f + __expf(-v)));
                }
            }
        }
    }
}

// ---------------------------------------------------------------------------
// conv2 as 9-shift implicit MFMA GEMM over bf16 NHWC. M=16384 px, N=256, K=1152.
// ---------------------------------------------------------------------------
__global__ __launch_bounds__(256) void conv2_mfma(
    const ushort* __restrict__ h1b, const ushort* __restrict__ w2b,
    const float* __restrict__ cb, const float* __restrict__ g,
    const float* __restrict__ bb, ushort* __restrict__ h2b)
{
    __shared__ __align__(16) ushort As[128 * 40];
    __shared__ __align__(16) ushort Bs[128 * 40];
    int t = threadIdx.x;
    int m0 = blockIdx.x * 128, n0 = blockIdx.y * 128;
    int b = m0 >> 12;
    int y0 = (m0 & 4095) >> 6;
    int lane = t & 63;
    int wm = ((t >> 6) & 1) * 64, wn = (t >> 7) * 64;
    int fr = lane & 15, fk = (lane >> 4) * 8;
    int r0 = t >> 2, c0 = (t & 3) * 8;
    floatx4 acc[4][4];
    #pragma unroll
    for (int i = 0; i < 4; ++i)
        #pragma unroll
        for (int j = 0; j < 4; ++j) acc[i][j] = {0.f, 0.f, 0.f, 0.f};
    const ushort* hb = h1b + (size_t)b * 4096 * 128;
    for (int s = 0; s < 9; ++s) {
        int ky = s / 3, kx = s % 3;
        int sy0 = y0 + ky - 1;
        int sx = r0 + kx - 1;
        bool vx = (unsigned)sx < 64u;
        bool v0 = vx && ((unsigned)sy0 < 64u);
        bool v1 = vx && ((unsigned)(sy0 + 1) < 64u);
        const ushort* a0p = hb + ((size_t)(sy0 * 64 + sx)) * 128 + c0;
        const ushort* a1p = a0p + 64 * 128;
        const ushort* wp = w2b + (size_t)(n0 + r0) * 1152 + s * 128 + c0;
        for (int ic0 = 0; ic0 < 128; ic0 += 32) {
            uint4 zz = make_uint4(0u, 0u, 0u, 0u);
            uint4 a0v = v0 ? *(const uint4*)(a0p + ic0) : zz;
            uint4 a1v = v1 ? *(const uint4*)(a1p + ic0) : zz;
            uint4 b0v = *(const uint4*)(wp + ic0);
            uint4 b1v = *(const uint4*)(wp + 64 * 1152 + ic0);
            __syncthreads();
            *(uint4*)&As[r0 * 40 + c0] = a0v;
            *(uint4*)&As[(r0 + 64) * 40 + c0] = a1v;
            *(uint4*)&Bs[r0 * 40 + c0] = b0v;
            *(uint4*)&Bs[(r0 + 64) * 40 + c0] = b1v;
            __syncthreads();
            bf16x8 af[4], bw[4];
            #pragma unroll
            for (int i = 0; i < 4; ++i)
                af[i] = *(const bf16x8*)&As[(wm + i * 16 + fr) * 40 + fk];
            #pragma unroll
            for (int j = 0; j < 4; ++j)
                bw[j] = *(const bf16x8*)&Bs[(wn + j * 16 + fr) * 40 + fk];
            #pragma unroll
            for (int i = 0; i < 4; ++i)
                #pragma unroll
                for (int j = 0; j < 4; ++j)
                    acc[i][j] = __builtin_amdgcn_mfma_f32_16x16x32_bf16(af[i], bw[j], acc[i][j], 0, 0, 0);
        }
    }
    int rbase = (lane >> 4) * 4, cc = lane & 15;
    #pragma unroll
    for (int j = 0; j < 4; ++j) {
        int n = n0 + wn + j * 16 + cc;
        float scl = g[n] * BN_RSQ, shf = bb[n], bv = cb[n];
        #pragma unroll
        for (int i = 0; i < 4; ++i) {
            #pragma unroll
            for (int r = 0; r < 4; ++r) {
                int m = m0 + wm + i * 16 + rbase + r;
                float v = gelu_f((acc[i][j][r] + bv) * scl + shf);
                h2b[(size_t)m * 256 + n] = f2bf(v);
            }
        }
    }
}

// Apb[m][s*256+ic] = h2b[b, 2oy+ky, 2ox+kx, ic]
__global__ void im2col_bf16(const ushort* __restrict__ h2b, ushort* __restrict__ Apb)
{
    int idx = blockIdx.x * 256 + threadIdx.x;          // 524288 uint4 chunks
    int k8 = idx & 127;
    int m = idx >> 7;
    int b = m >> 10, oy = (m >> 5) & 31, ox = m & 31;
    int s = k8 >> 5, ic8 = k8 & 31;
    int ky = s >> 1, kx = s & 1;
    uint4 v = *(const uint4*)(h2b + ((size_t)(b * 4096 + (2 * oy + ky) * 64 + 2 * ox + kx)) * 256 + ic8 * 8);
    *(uint4*)(Apb + (size_t)m * 1024 + k8 * 8) = v;
}

// ---------------------------------------------------------------------------
// fp32 tiled GEMM (small shapes): C = act(A @ W^T + bias)
// smode: 0 normal; 1 delta store C[(b*N+n)<<10 | l]; 2 x_proj split (xdbl/Bt/Ct)
// ---------------------------------------------------------------------------
template<int BM, int BN, int BK, int TM, int TN>
__global__ __launch_bounds__(256) void gemm_kernel(
    const float* __restrict__ A, int lda,
    const float* __restrict__ W, int ldw,
    const float* __restrict__ bias,
    float* __restrict__ C, int ldc,
    float* __restrict__ Bt_, float* __restrict__ Ct_,
    int M, int N, int K, int act, int smode)
{
    static_assert(BM * BK / 4 == 256 && BN * BK / 4 == 256, "staging shape");
    __shared__ float As[BK][BM + 4];
    __shared__ float Bs[BK][BN + 4];
    int t = threadIdx.x;
    int m0 = blockIdx.x * BM, n0 = blockIdx.y * BN;
    float acc[TM][TN];
    #pragma unroll
    for (int i = 0; i < TM; i++)
        #pragma unroll
        for (int j = 0; j < TN; j++) acc[i][j] = 0.f;
    const int LPR = BK / 4;
    int lr = t / LPR, lc4 = (t % LPR) * 4;
    int ty = t >> 4, tx = t & 15;
    for (int k0 = 0; k0 < K; k0 += BK) {
        float4 va = make_float4(0.f, 0.f, 0.f, 0.f);
        float4 vb = make_float4(0.f, 0.f, 0.f, 0.f);
        int ma = m0 + lr;
        if (ma < M) va = *(const float4*)(A + (size_t)ma * lda + k0 + lc4);
        int nb = n0 + lr;
        if (nb < N) vb = *(const float4*)(W + (size_t)nb * ldw + k0 + lc4);
        __syncthreads();
        As[lc4 + 0][lr] = va.x; As[lc4 + 1][lr] = va.y;
        As[lc4 + 2][lr] = va.z; As[lc4 + 3][lr] = va.w;
        Bs[lc4 + 0][lr] = vb.x; Bs[lc4 + 1][lr] = vb.y;
        Bs[lc4 + 2][lr] = vb.z; Bs[lc4 + 3][lr] = vb.w;
        __syncthreads();
        #pragma unroll
        for (int kk = 0; kk < BK; ++kk) {
            float a[TM], bfr[TN];
            #pragma unroll
            for (int i = 0; i < TM; i += 4)
                *(float4*)&a[i] = *(const float4*)&As[kk][ty * TM + i];
            #pragma unroll
            for (int j = 0; j < TN; j += 4)
                *(float4*)&bfr[j] = *(const float4*)&Bs[kk][tx * TN + j];
            #pragma unroll
            for (int i = 0; i < TM; i++)
                #pragma unroll
                for (int j = 0; j < TN; j++) acc[i][j] = fmaf(a[i], bfr[j], acc[i][j]);
        }
    }
    #pragma unroll
    for (int i = 0; i < TM; i++) {
        int m = m0 + ty * TM + i;
        if (m >= M) continue;
        int bI = m >> 10, lI = m & 1023;
        #pragma unroll
        for (int j = 0; j < TN; j++) {
            int n = n0 + tx * TN + j;
            if (n >= N) continue;
            float v = acc[i][j];
            if (bias) v += bias[n];
            if (act == 1) v = gelu_f(v);
            else if (act == 2) v = softplus_f(v);
            if (smode == 0) C[(size_t)m * ldc + n] = v;
            else if (smode == 1) C[((size_t)(bI * N + n) << 10) + lI] = v;
            else {
                if (n < 32) C[(size_t)m * 32 + n] = v;
                else if (n < 48) Bt_[((size_t)(bI * 16 + (n - 32)) << 10) + lI] = v;
                else Ct_[((size_t)(bI * 16 + (n - 48)) << 10) + lI] = v;
            }
        }
    }
}

// ---------------------------------------------------------------------------
// Depthwise conv1d (K=4, pad(1,2)) on xi[4096][512]; dual store xl fp32 + u fp32.
// ---------------------------------------------------------------------------
__global__ __launch_bounds__(256) void dwconv_dual(
    const float* __restrict__ xi, const float* __restrict__ cw,
    const float* __restrict__ cb, float* __restrict__ xl, float* __restrict__ u)
{
    __shared__ float tin[68][65];
    __shared__ float tout[64][65];
    int t = threadIdx.x;
    int bid = blockIdx.x;
    int dt_ = bid & 7, lt = (bid >> 3) & 15, b = bid >> 7;
    int d0 = dt_ * 64, l0 = lt * 64;
    int lane = t & 63, grp = t >> 6;
    for (int r = grp; r < 68; r += 4) {
        int l = l0 + r - 1;
        float v = 0.f;
        if ((unsigned)l < 1024u) v = xi[(size_t)(b * 1024 + l) * 512 + d0 + lane];
        tin[r][lane] = v;
    }
    __syncthreads();
    {
        int d = d0 + lane;
        float w0 = cw[d * 4 + 0], w1 = cw[d * 4 + 1], w2 = cw[d * 4 + 2], w3 = cw[d * 4 + 3];
        float bv = cb[d];
        int li0 = grp * 16;
        #pragma unroll
        for (int q = 0; q < 16; ++q) {
            int li = li0 + q;
            tout[li][lane] = bv + w0 * tin[li][lane] + w1 * tin[li + 1][lane]
                           + w2 * tin[li + 2][lane] + w3 * tin[li + 3][lane];
        }
    }
    __syncthreads();
    for (int r = grp; r < 64; r += 4)
        xl[(size_t)(b * 1024 + l0 + r) * 512 + d0 + lane] = tout[r][lane];
    for (int r = grp; r < 64; r += 4)
        u[(size_t)(b * 512 + d0 + r) * 1024 + l0 + lane] = tout[lane][r];
}

// ---------------------------------------------------------------------------
// Selective scan + fused silu gate -> ybb bf16 [b*1024+l][512].
// ---------------------------------------------------------------------------
__global__ __launch_bounds__(256) void scan_kernel(
    const float* __restrict__ delta, const float* __restrict__ u,
    const float* __restrict__ Bt, const float* __restrict__ Ct,
    const float* __restrict__ alog, const float* __restrict__ dssm,
    const ushort* __restrict__ resb, ushort* __restrict__ ybb)
{
    int wid = (blockIdx.x * 256 + threadIdx.x) >> 6;
    int lane = threadIdx.x & 63;
    int b = wid >> 7, dg = wid & 127;
    int dl = lane >> 4, n = lane & 15;
    int d = dg * 4 + dl;
    float Ac = -__expf(alog[d * 16 + n]);
    float Dd = dssm[d];
    const float4* dp = (const float4*)(delta + ((size_t)(b * 512 + d) << 10));
    const float4* up = (const float4*)(u + ((size_t)(b * 512 + d) << 10));
    const float4* Bp = (const float4*)(Bt + ((size_t)(b * 16 + n) << 10));
    const float4* Cp = (const float4*)(Ct + ((size_t)(b * 16 + n) << 10));
    const ushort* rp = resb + ((size_t)b << 19) + d;
    ushort* yp = ybb + ((size_t)b << 19) + d;
    float h = 0.f;
    float4 de = dp[0], uu = up[0], Bv = Bp[0], Cv = Cp[0];
    for (int it = 0; it < 256; ++it) {
        int nx = (it < 255) ? it + 1 : 255;
        float4 de2 = dp[nx], uu2 = up[nx], Bv2 = Bp[nx], Cv2 = Cp[nx];
        float p0, p1, p2, p3;
        h = __expf(de.x * Ac) * h + de.x * Bv.x * uu.x; p0 = h * Cv.x;
        h = __expf(de.y * Ac) * h + de.y * Bv.y * uu.y; p1 = h * Cv.y;
        h = __expf(de.z * Ac) * h + de.z * Bv.z * uu.z; p2 = h * Cv.z;
        h = __expf(de.w * Ac) * h + de.w * Bv.w * uu.w; p3 = h * Cv.w;
        #pragma unroll
        for (int off = 1; off < 16; off <<= 1) {
            p0 += __shfl_xor(p0, off);
            p1 += __shfl_xor(p1, off);
            p2 += __shfl_xor(p2, off);
            p3 += __shfl_xor(p3, off);
        }
        if (n == 0) {
            size_t l = (size_t)it * 4;
            float y0 = (p0 + uu.x * Dd) * bf2f(rp[(l + 0) * 512]);
            float y1 = (p1 + uu.y * Dd) * bf2f(rp[(l + 1) * 512]);
            float y2 = (p2 + uu.z * Dd) * bf2f(rp[(l + 2) * 512]);
            float y3 = (p3 + uu.w * Dd) * bf2f(rp[(l + 3) * 512]);
            yp[(l + 0) * 512] = f2bf(y0);
            yp[(l + 1) * 512] = f2bf(y1);
            yp[(l + 2) * 512] = f2bf(y2);
            yp[(l + 3) * 512] = f2bf(y3);
        }
        de = de2; uu = uu2; Bv = Bv2; Cv = Cv2;
    }
}

// s[row] = LN(o[row])*g + b + s[row]; also writes bf16 copy sb. One wave/row.
__global__ __launch_bounds__(256) void ln_res_kernel(
    const float* __restrict__ o, const float* __restrict__ g,
    const float* __restrict__ bb, float* __restrict__ s, ushort* __restrict__ sb)
{
    int row = blockIdx.x * 4 + (threadIdx.x >> 6);
    int lane = threadIdx.x & 63;
    const float4* orow = (const float4*)(o + (size_t)row * 256);
    float4 v = orow[lane];
    float sum = v.x + v.y + v.z + v.w;
    float sq = v.x * v.x + v.y * v.y + v.z * v.z + v.w * v.w;
    #pragma unroll
    for (int off = 1; off < 64; off <<= 1) {
        sum += __shfl_xor(sum, off);
        sq += __shfl_xor(sq, off);
    }
    float m = sum * (1.f / 256.f);
    float var = sq * (1.f / 256.f) - m * m;
    float rstd = rsqrtf(var + 1e-5f);
    float4 gg = ((const float4*)g)[lane];
    float4 bv = ((const float4*)bb)[lane];
    float4* srow = (float4*)(s + (size_t)row * 256);
    float4 sv = srow[lane];
    sv.x += (v.x - m) * rstd * gg.x + bv.x;
    sv.y += (v.y - m) * rstd * gg.y + bv.y;
    sv.z += (v.z - m) * rstd * gg.z + bv.z;
    sv.w += (v.w - m) * rstd * gg.w + bv.w;
    srow[lane] = sv;
    uint2 pk;
    pk.x = (uint)f2bf(sv.x) | ((uint)f2bf(sv.y) << 16);
    pk.y = (uint)f2bf(sv.z) | ((uint)f2bf(sv.w) << 16);
    *(uint2*)(sb + (size_t)row * 256 + lane * 4) = pk;
}

// mean over l then LN over 256 channels. grid 4 x 256.
__global__ __launch_bounds__(256) void pool_ln_kernel(
    const float* __restrict__ s, const float* __restrict__ nw,
    const float* __restrict__ nb, float* __restrict__ sln)
{
    int b = blockIdx.x, c = threadIdx.x;
    const float* p = s + (size_t)b * 262144 + c;
    float acc = 0.f;
    for (int l = 0; l < 1024; ++l) acc += p[(size_t)l * 256];
    float pooled = acc * (1.f / 1024.f);
    __shared__ float rs[4], rq[4];
    float sum = pooled, sq = pooled * pooled;
    #pragma unroll
    for (int off = 1; off < 64; off <<= 1) {
        sum += __shfl_xor(sum, off);
        sq += __shfl_xor(sq, off);
    }
    int w = threadIdx.x >> 6;
    if ((threadIdx.x & 63) == 0) { rs[w] = sum; rq[w] = sq; }
    __syncthreads();
    sum = rs[0] + rs[1] + rs[2] + rs[3];
    sq = rq[0] + rq[1] + rq[2] + rq[3];
    float m = sum * (1.f / 256.f);
    float var = sq * (1.f / 256.f) - m * m;
    float rstd = rsqrtf(var + 1e-5f);
    sln[b * 256 + c] = (pooled - m) * rstd * nw[c] + nb[c];
}

// softmax over 1000 logits per b
__global__ __launch_bounds__(256) void softmax_kernel(float* __restrict__ out)
{
    int b = threadIdx.x >> 6, lane = threadIdx.x & 63;
    const float* lg = out + b * 1000;
    float v[16];
    float mx = -1e30f;
    #pragma unroll
    for (int j = 0; j < 16; ++j) {
        int i = lane + j * 64;
        v[j] = (i < 1000) ? lg[i] : -1e30f;
        mx = fmaxf(mx, v[j]);
    }
    #pragma unroll
    for (int off = 1; off < 64; off <<= 1) mx = fmaxf(mx, __shfl_xor(mx, off));
    float sum = 0.f;
    #pragma unroll
    for (int j = 0; j < 16; ++j) {
        int i = lane + j * 64;
        if (i < 1000) { v[j] = __expf(v[j] - mx); sum += v[j]; }
    }
    #pragma unroll
    for (int off = 1; off < 64; off <<= 1) sum += __shfl_xor(sum, off);
    float inv = 1.f / sum;
    float* so = out + 4000 + b * 1000;
    #pragma unroll
    for (int j = 0; j < 16; ++j) {
        int i = lane + j * 64;
        if (i < 1000) so[i] = v[j] * inv;
    }
}

// ---------------------------------------------------------------------------
extern "C" void kernel_launch(void* const* d_in, const int* in_sizes, int n_in,
                              void* d_out, int out_size, void* d_ws, size_t ws_size,
                              hipStream_t stream)
{
    const float* x    = (const float*)d_in[0];
    const float* c1w  = (const float*)d_in[1];
    const float* c1b  = (const float*)d_in[2];
    const float* g1   = (const float*)d_in[3];
    const float* b1   = (const float*)d_in[4];
    const float* c2w  = (const float*)d_in[5];
    const float* c2b  = (const float*)d_in[6];
    const float* g2   = (const float*)d_in[7];
    const float* b2   = (const float*)d_in[8];
    const float* pw   = (const float*)d_in[9];
    const float* pb   = (const float*)d_in[10];
    const float* g3   = (const float*)d_in[11];
    const float* b3   = (const float*)d_in[12];
    const float* ipw  = (const float*)d_in[13];
    const float* ipb  = (const float*)d_in[14];
    const float* cw   = (const float*)d_in[15];
    const float* cb   = (const float*)d_in[16];
    const float* xpw  = (const float*)d_in[17];
    const float* dpw  = (const float*)d_in[18];
    const float* dpb  = (const float*)d_in[19];
    const float* alog = (const float*)d_in[20];
    const float* dssm = (const float*)d_in[21];
    const float* opw  = (const float*)d_in[22];
    const float* opb  = (const float*)d_in[23];
    const float* lnw  = (const float*)d_in[24];
    const float* lnb  = (const float*)d_in[25];
    const float* nw   = (const float*)d_in[26];
    const float* nb   = (const float*)d_in[27];
    const float* fcw  = (const float*)d_in[28];
    const float* fcb  = (const float*)d_in[29];
    float* out = (float*)d_out;
    float* wsf = (float*)d_ws;

    // ---- workspace layout (fl = float offsets), audited lifetimes ----
    // [0        , 1048576 )  s_    fp32 [4096,256]            persistent
    // [1048576  , 1572864 )  sb    bf16 [4096,256]            persistent
    // [1572864  , 3670016 )  xi    fp32 [4096,512]  | h2b bf16 [16384,256] | delta fp32 | obuf fp32
    // [3670016  , 4718592 )  resb  bf16 [4096,512]  (1048576 fl!)
    // [4718592  , 6815744 )  u_    fp32 [4,512,1024]| h1b bf16 [16384,128]
    // [6815744  , 8912896 )  xl    fp32 [4096,512]  | Apb bf16 [4096,1024] | ybb bf16 [4096,512]
    // [8912896  , 9043968 )  xdbl  fp32 [4096,32]
    // [9043968  , 9109504 )  Btb   fp32 [4,16,1024]
    // [9109504  , 9175040 )  Ctb   fp32 [4,16,1024]
    // [9175040  , 9699328 )  ipwb  bf16 [4,1024,256]
    // [9699328  , 9961472 )  opwb  bf16 [4,256,512]
    // [9961472  , 10108928)  w2b   bf16 [256,1152]
    // [10108928 , 10240000)  pwTb  bf16 [256,1024]
    // [10240000 , 10241024)  sln   fp32 [4,256]       total 41.0 MB
    float*  s_   = wsf;
    ushort* sb   = (ushort*)(wsf + 1048576);
    float*  xi   = wsf + 1572864;
    ushort* h2b  = (ushort*)(wsf + 1572864);
    float*  delta= wsf + 1572864;
    float*  obuf = wsf + 1572864;
    ushort* resb = (ushort*)(wsf + 3670016);
    float*  u_   = wsf + 4718592;
    ushort* h1b  = (ushort*)(wsf + 4718592);
    float*  xl   = wsf + 6815744;
    ushort* Apb  = (ushort*)(wsf + 6815744);
    ushort* ybb  = (ushort*)(wsf + 6815744);
    float*  xdbl = wsf + 8912896;
    float*  Btb  = wsf + 9043968;
    float*  Ctb  = wsf + 9109504;
    ushort* ipwb = (ushort*)(wsf + 9175040);
    ushort* opwb = (ushort*)(wsf + 9699328);
    ushort* w2b  = (ushort*)(wsf + 9961472);
    ushort* pwTb = (ushort*)(wsf + 10108928);
    float*  sln  = wsf + 10240000;

    // --- weight conversions ---
    hipLaunchKernelGGL(cvt_bf16, dim3(4096), dim3(256), 0, stream, ipw, ipwb, 1048576);
    hipLaunchKernelGGL(cvt_bf16, dim3(2048), dim3(256), 0, stream, opw, opwb, 524288);
    hipLaunchKernelGGL(w2b_kernel, dim3(1152), dim3(256), 0, stream, c2w, w2b);
    hipLaunchKernelGGL(pwTb_kernel, dim3(1024), dim3(256), 0, stream, pw, pwTb);

    // --- conv stem ---
    hipLaunchKernelGGL(conv1_nhwc, dim3(256), dim3(256), 0, stream, x, c1w, c1b, g1, b1, h1b);
    hipLaunchKernelGGL(conv2_mfma, dim3(128, 2), dim3(256), 0, stream, h1b, w2b, c2b, g2, b2, h2b);
    hipLaunchKernelGGL(im2col_bf16, dim3(2048), dim3(256), 0, stream, h2b, Apb);
    hipLaunchKernelGGL((mfma_gemm_bt<2>), dim3(32, 2), dim3(256), 0, stream,
                       Apb, 1024, pwTb, 1024, pb, g3, b3, s_, sb, 256, 1024);

    // --- mamba blocks ---
    for (int i = 0; i < 4; ++i) {
        const ushort* ipwb_i = ipwb + (size_t)i * 1024 * 256;
        const float*  ipb_i  = ipb + i * 1024;
        const float*  cw_i   = cw + i * 512 * 4;
        const float*  cb_i   = cb + i * 512;
        const float*  xpw_i  = xpw + (size_t)i * 64 * 512;
        const float*  dpw_i  = dpw + (size_t)i * 512 * 32;
        const float*  dpb_i  = dpb + i * 512;
        const float*  alog_i = alog + (size_t)i * 512 * 16;
        const float*  dssm_i = dssm + i * 512;
        const ushort* opwb_i = opwb + (size_t)i * 256 * 512;
        const float*  opb_i  = opb + i * 256;
        const float*  lnw_i  = lnw + i * 256;
        const float*  lnb_i  = lnb + i * 256;

        // in_proj (bf16 MFMA): xi fp32 + silu(res) bf16
        hipLaunchKernelGGL((mfma_gemm_bt<3>), dim3(32, 8), dim3(256), 0, stream,
                           sb, 256, ipwb_i, 256, ipb_i, nullptr, nullptr, xi, resb, 0, 256);
        hipLaunchKernelGGL(dwconv_dual, dim3(512), dim3(256), 0, stream, xi, cw_i, cb_i, xl, u_);
        // x_proj (fp32) with fused B/C transpose
        hipLaunchKernelGGL((gemm_kernel<64, 64, 16, 4, 4>), dim3(64, 1), dim3(256), 0, stream,
                           xl, 512, xpw_i, 512, nullptr, xdbl, 32, Btb, Ctb,
                           4096, 64, 512, 0, 2);
        // dt_proj (fp32) + softplus, transposed store -> delta[b,d,l]
        hipLaunchKernelGGL((gemm_kernel<64, 64, 16, 4, 4>), dim3(64, 8), dim3(256), 0, stream,
                           xdbl, 32, dpw_i, 32, dpb_i, delta, 512, nullptr, nullptr,
                           4096, 512, 32, 2, 1);
        // scan + gate -> ybb bf16
        hipLaunchKernelGGL(scan_kernel, dim3(128), dim3(256), 0, stream,
                           delta, u_, Btb, Ctb, alog_i, dssm_i, resb, ybb);
        // out_proj (bf16 MFMA) -> obuf fp32
        hipLaunchKernelGGL((mfma_gemm_bt<0>), dim3(32, 2), dim3(256), 0, stream,
                           ybb, 512, opwb_i, 512, opb_i, nullptr, nullptr, obuf, nullptr, 256, 512);
        hipLaunchKernelGGL(ln_res_kernel, dim3(1024), dim3(256), 0, stream,
                           obuf, lnw_i, lnb_i, s_, sb);
    }

    // --- head ---
    hipLaunchKernelGGL(pool_ln_kernel, dim3(4), dim3(256), 0, stream, s_, nw, nb, sln);
    hipLaunchKernelGGL((gemm_kernel<64, 64, 16, 4, 4>), dim3(1, 16), dim3(256), 0, stream,
                       sln, 256, fcw, 256, fcb, out, 1000, nullptr, nullptr,
                       4, 1000, 256, 0, 0);
    hipLaunchKernelGGL(softmax_kernel, dim3(1), dim3(256), 0, stream, out);
}

// Round 5
// 1175.864 us; speedup vs baseline: 2.0620x; 1.1792x over previous
//
#include <hip/hip_runtime.h>
#include <math.h>

// ---------------------------------------------------------------------------
// FastImageMamba forward. R5: R4 + chunked two-pass selective scan
// (8 chunks of 128 over L; 8x wave parallelism; was latency-bound at 2 waves/CU).
// B=4, DM=256, NL=4, NC=1000, DI=512, NS=16, DTR=32, K=4, L=1024, H=W=64
// ---------------------------------------------------------------------------

#define BN_RSQ 0.99999500003749969f   // 1/sqrt(1+1e-5)

typedef unsigned int uint;
typedef unsigned short ushort;
typedef __bf16 bf16x8 __attribute__((ext_vector_type(8)));
typedef float floatx4 __attribute__((ext_vector_type(4)));

__device__ __forceinline__ float gelu_f(float v) {
    return 0.5f * v * (1.0f + erff(v * 0.70710678118654752f));
}
__device__ __forceinline__ float softplus_f(float v) {
    return (v > 20.f) ? v : log1pf(expf(v));
}
__device__ __forceinline__ ushort f2bf(float f) {
    uint x = __float_as_uint(f);
    x += 0x7fffu + ((x >> 16) & 1u);
    return (ushort)(x >> 16);
}
__device__ __forceinline__ float bf2f(ushort u) {
    return __uint_as_float((uint)u << 16);
}

// float -> bf16 elementwise
__global__ void cvt_bf16(const float* __restrict__ src, ushort* __restrict__ dst, int n)
{
    int i = blockIdx.x * 256 + threadIdx.x;
    if (i < n) dst[i] = f2bf(src[i]);
}

// w2b[oc][s*128+ic] = bf16(c2w[oc][ic][ky][kx]), s=ky*3+kx
__global__ void w2b_kernel(const float* __restrict__ c2w, ushort* __restrict__ w2b)
{
    int idx = blockIdx.x * 256 + threadIdx.x;          // 294912
    int oc = idx / 1152, k = idx % 1152;
    int s = k >> 7, ic = k & 127;
    w2b[idx] = f2bf(c2w[(size_t)(oc * 128 + ic) * 9 + s]);
}

// pwTb[oc][s*256+ic] = bf16(pw[oc][ic][ky][kx]), s=ky*2+kx
__global__ void pwTb_kernel(const float* __restrict__ pw, ushort* __restrict__ pwTb)
{
    int idx = blockIdx.x * 256 + threadIdx.x;          // 262144
    int oc = idx >> 10, k = idx & 1023;
    int s = k >> 8, ic = k & 255;
    int ky = s >> 1, kx = s & 1;
    pwTb[idx] = f2bf(pw[((size_t)(oc * 256 + ic) * 2 + ky) * 2 + kx]);
}

// ---------------------------------------------------------------------------
// conv1: 3x3 s1p1, IC=3 -> OC=128, NCHW fp32 in, NHWC bf16 out (+bias+BN+GELU)
// ---------------------------------------------------------------------------
__global__ __launch_bounds__(256) void conv1_nhwc(
    const float* __restrict__ x, const float* __restrict__ w,
    const float* __restrict__ cb, const float* __restrict__ g,
    const float* __restrict__ bb, ushort* __restrict__ out)
{
    __shared__ float tin[3][3][64];
    __shared__ float ws[3456];
    int t = threadIdx.x;
    int b = blockIdx.x >> 6, y = blockIdx.x & 63;
    for (int i = t; i < 3456; i += 256) ws[i] = w[i];
    for (int i = t; i < 576; i += 256) {
        int ic = i / 192, r = (i >> 6) % 3, xx = i & 63;
        int gy = y + r - 1;
        tin[ic][r][xx] = ((unsigned)gy < 64u) ? x[((b * 3 + ic) * 64 + gy) * 64 + xx] : 0.f;
    }
    __syncthreads();
    int tx = t & 15, ty = t >> 4;
    int oc0 = tx * 8, px0 = ty * 4;
    float acc[4][8];
    #pragma unroll
    for (int p = 0; p < 4; ++p)
        #pragma unroll
        for (int o = 0; o < 8; ++o) acc[p][o] = 0.f;
    for (int ic = 0; ic < 3; ++ic)
        #pragma unroll
        for (int ky = 0; ky < 3; ++ky)
            #pragma unroll
            for (int kx = 0; kx < 3; ++kx) {
                float av[4];
                #pragma unroll
                for (int p = 0; p < 4; ++p) {
                    int xx = px0 + p + kx - 1;
                    av[p] = ((unsigned)xx < 64u) ? tin[ic][ky][xx] : 0.f;
                }
                #pragma unroll
                for (int o = 0; o < 8; ++o) {
                    float wv = ws[(oc0 + o) * 27 + ic * 9 + ky * 3 + kx];
                    #pragma unroll
                    for (int p = 0; p < 4; ++p) acc[p][o] = fmaf(av[p], wv, acc[p][o]);
                }
            }
    #pragma unroll
    for (int p = 0; p < 4; ++p) {
        uint pk[4];
        #pragma unroll
        for (int o2 = 0; o2 < 4; ++o2) {
            int oc = oc0 + o2 * 2;
            float v0 = gelu_f((acc[p][o2 * 2] + cb[oc]) * (g[oc] * BN_RSQ) + bb[oc]);
            float v1 = gelu_f((acc[p][o2 * 2 + 1] + cb[oc + 1]) * (g[oc + 1] * BN_RSQ) + bb[oc + 1]);
            pk[o2] = (uint)f2bf(v0) | ((uint)f2bf(v1) << 16);
        }
        uint4 vv = make_uint4(pk[0], pk[1], pk[2], pk[3]);
        *(uint4*)(out + ((size_t)((b * 64 + y) * 64 + px0 + p)) * 128 + oc0) = vv;
    }
}

// ---------------------------------------------------------------------------
// Generic bf16 MFMA GEMM (A @ W^T), 128x128 tile, BK=32, 4 waves.
// EPI: 0 = +bias -> fp32 Cf[ldc]
//      1 = +bias,BN,GELU -> bf16 Cb[ldc]
//      2 = +bias,BN,GELU -> fp32 Cf + bf16 Cb (same ldc)
//      3 = in_proj: n<512 -> fp32 Cf[m*512+n]; n>=512 -> bf16 silu -> Cb[m*512+n-512]
// ---------------------------------------------------------------------------
template<int EPI>
__global__ __launch_bounds__(256) void mfma_gemm_bt(
    const ushort* __restrict__ A, int lda,
    const ushort* __restrict__ W, int ldw,
    const float* __restrict__ bias,
    const float* __restrict__ bnG, const float* __restrict__ bnB,
    float* __restrict__ Cf, ushort* __restrict__ Cb, int ldc, int K)
{
    __shared__ __align__(16) ushort As[128 * 40];
    __shared__ __align__(16) ushort Bs[128 * 40];
    int t = threadIdx.x;
    int m0 = blockIdx.x * 128, n0 = blockIdx.y * 128;
    int lane = t & 63;
    int wm = ((t >> 6) & 1) * 64, wn = (t >> 7) * 64;
    int fr = lane & 15, fk = (lane >> 4) * 8;
    int r0 = t >> 2, c0 = (t & 3) * 8;
    floatx4 acc[4][4];
    #pragma unroll
    for (int i = 0; i < 4; ++i)
        #pragma unroll
        for (int j = 0; j < 4; ++j) acc[i][j] = {0.f, 0.f, 0.f, 0.f};
    const ushort* Ap0 = A + (size_t)(m0 + r0) * lda + c0;
    const ushort* Ap1 = A + (size_t)(m0 + r0 + 64) * lda + c0;
    const ushort* Wp0 = W + (size_t)(n0 + r0) * ldw + c0;
    const ushort* Wp1 = W + (size_t)(n0 + r0 + 64) * ldw + c0;
    for (int k0 = 0; k0 < K; k0 += 32) {
        uint4 a0v = *(const uint4*)(Ap0 + k0);
        uint4 a1v = *(const uint4*)(Ap1 + k0);
        uint4 b0v = *(const uint4*)(Wp0 + k0);
        uint4 b1v = *(const uint4*)(Wp1 + k0);
        __syncthreads();
        *(uint4*)&As[r0 * 40 + c0] = a0v;
        *(uint4*)&As[(r0 + 64) * 40 + c0] = a1v;
        *(uint4*)&Bs[r0 * 40 + c0] = b0v;
        *(uint4*)&Bs[(r0 + 64) * 40 + c0] = b1v;
        __syncthreads();
        bf16x8 af[4], bw[4];
        #pragma unroll
        for (int i = 0; i < 4; ++i)
            af[i] = *(const bf16x8*)&As[(wm + i * 16 + fr) * 40 + fk];
        #pragma unroll
        for (int j = 0; j < 4; ++j)
            bw[j] = *(const bf16x8*)&Bs[(wn + j * 16 + fr) * 40 + fk];
        #pragma unroll
        for (int i = 0; i < 4; ++i)
            #pragma unroll
            for (int j = 0; j < 4; ++j)
                acc[i][j] = __builtin_amdgcn_mfma_f32_16x16x32_bf16(af[i], bw[j], acc[i][j], 0, 0, 0);
    }
    int rbase = (lane >> 4) * 4, cc = lane & 15;
    #pragma unroll
    for (int j = 0; j < 4; ++j) {
        int n = n0 + wn + j * 16 + cc;
        float bv = bias ? bias[n] : 0.f;
        float scl = 0.f, shf = 0.f;
        if (EPI == 1 || EPI == 2) { scl = bnG[n] * BN_RSQ; shf = bnB[n]; }
        #pragma unroll
        for (int i = 0; i < 4; ++i) {
            #pragma unroll
            for (int r = 0; r < 4; ++r) {
                int m = m0 + wm + i * 16 + rbase + r;
                float v = acc[i][j][r] + bv;
                if (EPI == 1 || EPI == 2) v = gelu_f(v * scl + shf);
                if (EPI == 0) {
                    Cf[(size_t)m * ldc + n] = v;
                } else if (EPI == 1) {
                    Cb[(size_t)m * ldc + n] = f2bf(v);
                } else if (EPI == 2) {
                    Cf[(size_t)m * ldc + n] = v;
                    Cb[(size_t)m * ldc + n] = f2bf(v);
                } else {
                    if (n < 512) Cf[(size_t)m * 512 + n] = v;
                    else Cb[(size_t)m * 512 + (n - 512)] = f2bf(v / (1.f + __expf(-v)));
                }
            }
        }
    }
}

// ---------------------------------------------------------------------------
// conv2 as 9-shift implicit MFMA GEMM over bf16 NHWC. M=16384 px, N=256, K=1152.
// ---------------------------------------------------------------------------
__global__ __launch_bounds__(256) void conv2_mfma(
    const ushort* __restrict__ h1b, const ushort* __restrict__ w2b,
    const float* __restrict__ cb, const float* __restrict__ g,
    const float* __restrict__ bb, ushort* __restrict__ h2b)
{
    __shared__ __align__(16) ushort As[128 * 40];
    __shared__ __align__(16) ushort Bs[128 * 40];
    int t = threadIdx.x;
    int m0 = blockIdx.x * 128, n0 = blockIdx.y * 128;
    int b = m0 >> 12;
    int y0 = (m0 & 4095) >> 6;
    int lane = t & 63;
    int wm = ((t >> 6) & 1) * 64, wn = (t >> 7) * 64;
    int fr = lane & 15, fk = (lane >> 4) * 8;
    int r0 = t >> 2, c0 = (t & 3) * 8;
    floatx4 acc[4][4];
    #pragma unroll
    for (int i = 0; i < 4; ++i)
        #pragma unroll
        for (int j = 0; j < 4; ++j) acc[i][j] = {0.f, 0.f, 0.f, 0.f};
    const ushort* hb = h1b + (size_t)b * 4096 * 128;
    for (int s = 0; s < 9; ++s) {
        int ky = s / 3, kx = s % 3;
        int sy0 = y0 + ky - 1;
        int sx = r0 + kx - 1;
        bool vx = (unsigned)sx < 64u;
        bool v0 = vx && ((unsigned)sy0 < 64u);
        bool v1 = vx && ((unsigned)(sy0 + 1) < 64u);
        const ushort* a0p = hb + ((size_t)(sy0 * 64 + sx)) * 128 + c0;
        const ushort* a1p = a0p + 64 * 128;
        const ushort* wp = w2b + (size_t)(n0 + r0) * 1152 + s * 128 + c0;
        for (int ic0 = 0; ic0 < 128; ic0 += 32) {
            uint4 zz = make_uint4(0u, 0u, 0u, 0u);
            uint4 a0v = v0 ? *(const uint4*)(a0p + ic0) : zz;
            uint4 a1v = v1 ? *(const uint4*)(a1p + ic0) : zz;
            uint4 b0v = *(const uint4*)(wp + ic0);
            uint4 b1v = *(const uint4*)(wp + 64 * 1152 + ic0);
            __syncthreads();
            *(uint4*)&As[r0 * 40 + c0] = a0v;
            *(uint4*)&As[(r0 + 64) * 40 + c0] = a1v;
            *(uint4*)&Bs[r0 * 40 + c0] = b0v;
            *(uint4*)&Bs[(r0 + 64) * 40 + c0] = b1v;
            __syncthreads();
            bf16x8 af[4], bw[4];
            #pragma unroll
            for (int i = 0; i < 4; ++i)
                af[i] = *(const bf16x8*)&As[(wm + i * 16 + fr) * 40 + fk];
            #pragma unroll
            for (int j = 0; j < 4; ++j)
                bw[j] = *(const bf16x8*)&Bs[(wn + j * 16 + fr) * 40 + fk];
            #pragma unroll
            for (int i = 0; i < 4; ++i)
                #pragma unroll
                for (int j = 0; j < 4; ++j)
                    acc[i][j] = __builtin_amdgcn_mfma_f32_16x16x32_bf16(af[i], bw[j], acc[i][j], 0, 0, 0);
        }
    }
    int rbase = (lane >> 4) * 4, cc = lane & 15;
    #pragma unroll
    for (int j = 0; j < 4; ++j) {
        int n = n0 + wn + j * 16 + cc;
        float scl = g[n] * BN_RSQ, shf = bb[n], bv = cb[n];
        #pragma unroll
        for (int i = 0; i < 4; ++i) {
            #pragma unroll
            for (int r = 0; r < 4; ++r) {
                int m = m0 + wm + i * 16 + rbase + r;
                float v = gelu_f((acc[i][j][r] + bv) * scl + shf);
                h2b[(size_t)m * 256 + n] = f2bf(v);
            }
        }
    }
}

// Apb[m][s*256+ic] = h2b[b, 2oy+ky, 2ox+kx, ic]
__global__ void im2col_bf16(const ushort* __restrict__ h2b, ushort* __restrict__ Apb)
{
    int idx = blockIdx.x * 256 + threadIdx.x;          // 524288 uint4 chunks
    int k8 = idx & 127;
    int m = idx >> 7;
    int b = m >> 10, oy = (m >> 5) & 31, ox = m & 31;
    int s = k8 >> 5, ic8 = k8 & 31;
    int ky = s >> 1, kx = s & 1;
    uint4 v = *(const uint4*)(h2b + ((size_t)(b * 4096 + (2 * oy + ky) * 64 + 2 * ox + kx)) * 256 + ic8 * 8);
    *(uint4*)(Apb + (size_t)m * 1024 + k8 * 8) = v;
}

// ---------------------------------------------------------------------------
// fp32 tiled GEMM (small shapes): C = act(A @ W^T + bias)
// smode: 0 normal; 1 delta store C[(b*N+n)<<10 | l]; 2 x_proj split (xdbl/Bt/Ct)
// ---------------------------------------------------------------------------
template<int BM, int BN, int BK, int TM, int TN>
__global__ __launch_bounds__(256) void gemm_kernel(
    const float* __restrict__ A, int lda,
    const float* __restrict__ W, int ldw,
    const float* __restrict__ bias,
    float* __restrict__ C, int ldc,
    float* __restrict__ Bt_, float* __restrict__ Ct_,
    int M, int N, int K, int act, int smode)
{
    static_assert(BM * BK / 4 == 256 && BN * BK / 4 == 256, "staging shape");
    __shared__ float As[BK][BM + 4];
    __shared__ float Bs[BK][BN + 4];
    int t = threadIdx.x;
    int m0 = blockIdx.x * BM, n0 = blockIdx.y * BN;
    float acc[TM][TN];
    #pragma unroll
    for (int i = 0; i < TM; i++)
        #pragma unroll
        for (int j = 0; j < TN; j++) acc[i][j] = 0.f;
    const int LPR = BK / 4;
    int lr = t / LPR, lc4 = (t % LPR) * 4;
    int ty = t >> 4, tx = t & 15;
    for (int k0 = 0; k0 < K; k0 += BK) {
        float4 va = make_float4(0.f, 0.f, 0.f, 0.f);
        float4 vb = make_float4(0.f, 0.f, 0.f, 0.f);
        int ma = m0 + lr;
        if (ma < M) va = *(const float4*)(A + (size_t)ma * lda + k0 + lc4);
        int nb = n0 + lr;
        if (nb < N) vb = *(const float4*)(W + (size_t)nb * ldw + k0 + lc4);
        __syncthreads();
        As[lc4 + 0][lr] = va.x; As[lc4 + 1][lr] = va.y;
        As[lc4 + 2][lr] = va.z; As[lc4 + 3][lr] = va.w;
        Bs[lc4 + 0][lr] = vb.x; Bs[lc4 + 1][lr] = vb.y;
        Bs[lc4 + 2][lr] = vb.z; Bs[lc4 + 3][lr] = vb.w;
        __syncthreads();
        #pragma unroll
        for (int kk = 0; kk < BK; ++kk) {
            float a[TM], bfr[TN];
            #pragma unroll
            for (int i = 0; i < TM; i += 4)
                *(float4*)&a[i] = *(const float4*)&As[kk][ty * TM + i];
            #pragma unroll
            for (int j = 0; j < TN; j += 4)
                *(float4*)&bfr[j] = *(const float4*)&Bs[kk][tx * TN + j];
            #pragma unroll
            for (int i = 0; i < TM; i++)
                #pragma unroll
                for (int j = 0; j < TN; j++) acc[i][j] = fmaf(a[i], bfr[j], acc[i][j]);
        }
    }
    #pragma unroll
    for (int i = 0; i < TM; i++) {
        int m = m0 + ty * TM + i;
        if (m >= M) continue;
        int bI = m >> 10, lI = m & 1023;
        #pragma unroll
        for (int j = 0; j < TN; j++) {
            int n = n0 + tx * TN + j;
            if (n >= N) continue;
            float v = acc[i][j];
            if (bias) v += bias[n];
            if (act == 1) v = gelu_f(v);
            else if (act == 2) v = softplus_f(v);
            if (smode == 0) C[(size_t)m * ldc + n] = v;
            else if (smode == 1) C[((size_t)(bI * N + n) << 10) + lI] = v;
            else {
                if (n < 32) C[(size_t)m * 32 + n] = v;
                else if (n < 48) Bt_[((size_t)(bI * 16 + (n - 32)) << 10) + lI] = v;
                else Ct_[((size_t)(bI * 16 + (n - 48)) << 10) + lI] = v;
            }
        }
    }
}

// ---------------------------------------------------------------------------
// Depthwise conv1d (K=4, pad(1,2)) on xi[4096][512]; dual store xl fp32 + u fp32.
// ---------------------------------------------------------------------------
__global__ __launch_bounds__(256) void dwconv_dual(
    const float* __restrict__ xi, const float* __restrict__ cw,
    const float* __restrict__ cb, float* __restrict__ xl, float* __restrict__ u)
{
    __shared__ float tin[68][65];
    __shared__ float tout[64][65];
    int t = threadIdx.x;
    int bid = blockIdx.x;
    int dt_ = bid & 7, lt = (bid >> 3) & 15, b = bid >> 7;
    int d0 = dt_ * 64, l0 = lt * 64;
    int lane = t & 63, grp = t >> 6;
    for (int r = grp; r < 68; r += 4) {
        int l = l0 + r - 1;
        float v = 0.f;
        if ((unsigned)l < 1024u) v = xi[(size_t)(b * 1024 + l) * 512 + d0 + lane];
        tin[r][lane] = v;
    }
    __syncthreads();
    {
        int d = d0 + lane;
        float w0 = cw[d * 4 + 0], w1 = cw[d * 4 + 1], w2 = cw[d * 4 + 2], w3 = cw[d * 4 + 3];
        float bv = cb[d];
        int li0 = grp * 16;
        #pragma unroll
        for (int q = 0; q < 16; ++q) {
            int li = li0 + q;
            tout[li][lane] = bv + w0 * tin[li][lane] + w1 * tin[li + 1][lane]
                           + w2 * tin[li + 2][lane] + w3 * tin[li + 3][lane];
        }
    }
    __syncthreads();
    for (int r = grp; r < 64; r += 4)
        xl[(size_t)(b * 1024 + l0 + r) * 512 + d0 + lane] = tout[r][lane];
    for (int r = grp; r < 64; r += 4)
        u[(size_t)(b * 512 + d0 + r) * 1024 + l0 + lane] = tout[lane][r];
}

// ---------------------------------------------------------------------------
// Chunked selective scan, pass 1: per-chunk summaries.
// 4096 waves: wid = b(4) x dg(128) x ch(8); lane = dl*16+n; 128 timesteps/chunk.
// P = prod exp(delta*A), hF = local h (h0=0). Stored [b][dg][lane][8].
// ---------------------------------------------------------------------------
__global__ __launch_bounds__(256) void scan_part1(
    const float* __restrict__ delta, const float* __restrict__ u,
    const float* __restrict__ Bt, const float* __restrict__ alog,
    float* __restrict__ Psum, float* __restrict__ hFsum)
{
    int wid = (blockIdx.x * 256 + threadIdx.x) >> 6;
    int lane = threadIdx.x & 63;
    int ch = wid & 7, dg = (wid >> 3) & 127, b = wid >> 10;
    int dl = lane >> 4, n = lane & 15;
    int d = dg * 4 + dl;
    float Ac = -__expf(alog[d * 16 + n]);
    const float4* dp = (const float4*)(delta + ((size_t)(b * 512 + d) << 10)) + ch * 32;
    const float4* up = (const float4*)(u + ((size_t)(b * 512 + d) << 10)) + ch * 32;
    const float4* Bp = (const float4*)(Bt + ((size_t)(b * 16 + n) << 10)) + ch * 32;
    float h = 0.f, P = 1.f;
    float4 deb[2], uub[2], Bvb[2];
    deb[0] = dp[0]; uub[0] = up[0]; Bvb[0] = Bp[0];
    deb[1] = dp[1]; uub[1] = up[1]; Bvb[1] = Bp[1];
    for (int it = 0; it < 32; ++it) {
        float4 de = deb[it & 1], uu = uub[it & 1], Bv = Bvb[it & 1];
        if (it + 2 < 32) {
            deb[it & 1] = dp[it + 2]; uub[it & 1] = up[it + 2]; Bvb[it & 1] = Bp[it + 2];
        }
        float a;
        a = __expf(de.x * Ac); h = a * h + de.x * Bv.x * uu.x; P *= a;
        a = __expf(de.y * Ac); h = a * h + de.y * Bv.y * uu.y; P *= a;
        a = __expf(de.z * Ac); h = a * h + de.z * Bv.z * uu.z; P *= a;
        a = __expf(de.w * Ac); h = a * h + de.w * Bv.w * uu.w; P *= a;
    }
    size_t si = (((size_t)(b * 128 + dg)) * 64 + lane) * 8 + ch;
    Psum[si] = P;
    hFsum[si] = h;
}

// ---------------------------------------------------------------------------
// Chunked selective scan, pass 2: combine predecessor summaries in-register,
// rerun local scan from correct H_in, y = reduce_n(h*C) + u*D, fuse silu gate,
// write ybb bf16 [b*1024+l][512].
// ---------------------------------------------------------------------------
__global__ __launch_bounds__(256) void scan_part2(
    const float* __restrict__ delta, const float* __restrict__ u,
    const float* __restrict__ Bt, const float* __restrict__ Ct,
    const float* __restrict__ alog, const float* __restrict__ dssm,
    const ushort* __restrict__ resb, ushort* __restrict__ ybb,
    const float* __restrict__ Psum, const float* __restrict__ hFsum)
{
    int wid = (blockIdx.x * 256 + threadIdx.x) >> 6;
    int lane = threadIdx.x & 63;
    int ch = wid & 7, dg = (wid >> 3) & 127, b = wid >> 10;
    int dl = lane >> 4, n = lane & 15;
    int d = dg * 4 + dl;
    float Ac = -__expf(alog[d * 16 + n]);
    float Dd = dssm[d];
    const float4* dp = (const float4*)(delta + ((size_t)(b * 512 + d) << 10)) + ch * 32;
    const float4* up = (const float4*)(u + ((size_t)(b * 512 + d) << 10)) + ch * 32;
    const float4* Bp = (const float4*)(Bt + ((size_t)(b * 16 + n) << 10)) + ch * 32;
    const float4* Cp = (const float4*)(Ct + ((size_t)(b * 16 + n) << 10)) + ch * 32;
    const ushort* rp = resb + ((size_t)b << 19) + d + (size_t)ch * 128 * 512;
    ushort* yp = ybb + ((size_t)b << 19) + d + (size_t)ch * 128 * 512;

    float h = 0.f;
    if (ch > 0) {
        size_t sbase = (((size_t)(b * 128 + dg)) * 64 + lane) * 8;
        float4 Pv0 = *(const float4*)(Psum + sbase);
        float4 Pv1 = *(const float4*)(Psum + sbase + 4);
        float4 hv0 = *(const float4*)(hFsum + sbase);
        float4 hv1 = *(const float4*)(hFsum + sbase + 4);
        float Pa[8] = {Pv0.x, Pv0.y, Pv0.z, Pv0.w, Pv1.x, Pv1.y, Pv1.z, Pv1.w};
        float ha[8] = {hv0.x, hv0.y, hv0.z, hv0.w, hv1.x, hv1.y, hv1.z, hv1.w};
        for (int cc = 0; cc < ch; ++cc) h = Pa[cc] * h + ha[cc];
    }

    float4 deb[2], uub[2], Bvb[2], Cvb[2];
    deb[0] = dp[0]; uub[0] = up[0]; Bvb[0] = Bp[0]; Cvb[0] = Cp[0];
    deb[1] = dp[1]; uub[1] = up[1]; Bvb[1] = Bp[1]; Cvb[1] = Cp[1];
    for (int it = 0; it < 32; ++it) {
        float4 de = deb[it & 1], uu = uub[it & 1], Bv = Bvb[it & 1], Cv = Cvb[it & 1];
        if (it + 2 < 32) {
            deb[it & 1] = dp[it + 2]; uub[it & 1] = up[it + 2];
            Bvb[it & 1] = Bp[it + 2]; Cvb[it & 1] = Cp[it + 2];
        }
        float p0, p1, p2, p3;
        h = __expf(de.x * Ac) * h + de.x * Bv.x * uu.x; p0 = h * Cv.x;
        h = __expf(de.y * Ac) * h + de.y * Bv.y * uu.y; p1 = h * Cv.y;
        h = __expf(de.z * Ac) * h + de.z * Bv.z * uu.z; p2 = h * Cv.z;
        h = __expf(de.w * Ac) * h + de.w * Bv.w * uu.w; p3 = h * Cv.w;
        #pragma unroll
        for (int off = 1; off < 16; off <<= 1) {
            p0 += __shfl_xor(p0, off);
            p1 += __shfl_xor(p1, off);
            p2 += __shfl_xor(p2, off);
            p3 += __shfl_xor(p3, off);
        }
        if (n == 0) {
            size_t l = (size_t)it * 4;
            float y0 = (p0 + uu.x * Dd) * bf2f(rp[(l + 0) * 512]);
            float y1 = (p1 + uu.y * Dd) * bf2f(rp[(l + 1) * 512]);
            float y2 = (p2 + uu.z * Dd) * bf2f(rp[(l + 2) * 512]);
            float y3 = (p3 + uu.w * Dd) * bf2f(rp[(l + 3) * 512]);
            yp[(l + 0) * 512] = f2bf(y0);
            yp[(l + 1) * 512] = f2bf(y1);
            yp[(l + 2) * 512] = f2bf(y2);
            yp[(l + 3) * 512] = f2bf(y3);
        }
    }
}

// s[row] = LN(o[row])*g + b + s[row]; also writes bf16 copy sb. One wave/row.
__global__ __launch_bounds__(256) void ln_res_kernel(
    const float* __restrict__ o, const float* __restrict__ g,
    const float* __restrict__ bb, float* __restrict__ s, ushort* __restrict__ sb)
{
    int row = blockIdx.x * 4 + (threadIdx.x >> 6);
    int lane = threadIdx.x & 63;
    const float4* orow = (const float4*)(o + (size_t)row * 256);
    float4 v = orow[lane];
    float sum = v.x + v.y + v.z + v.w;
    float sq = v.x * v.x + v.y * v.y + v.z * v.z + v.w * v.w;
    #pragma unroll
    for (int off = 1; off < 64; off <<= 1) {
        sum += __shfl_xor(sum, off);
        sq += __shfl_xor(sq, off);
    }
    float m = sum * (1.f / 256.f);
    float var = sq * (1.f / 256.f) - m * m;
    float rstd = rsqrtf(var + 1e-5f);
    float4 gg = ((const float4*)g)[lane];
    float4 bv = ((const float4*)bb)[lane];
    float4* srow = (float4*)(s + (size_t)row * 256);
    float4 sv = srow[lane];
    sv.x += (v.x - m) * rstd * gg.x + bv.x;
    sv.y += (v.y - m) * rstd * gg.y + bv.y;
    sv.z += (v.z - m) * rstd * gg.z + bv.z;
    sv.w += (v.w - m) * rstd * gg.w + bv.w;
    srow[lane] = sv;
    uint2 pk;
    pk.x = (uint)f2bf(sv.x) | ((uint)f2bf(sv.y) << 16);
    pk.y = (uint)f2bf(sv.z) | ((uint)f2bf(sv.w) << 16);
    *(uint2*)(sb + (size_t)row * 256 + lane * 4) = pk;
}

// mean over l then LN over 256 channels. grid 4 x 256.
__global__ __launch_bounds__(256) void pool_ln_kernel(
    const float* __restrict__ s, const float* __restrict__ nw,
    const float* __restrict__ nb, float* __restrict__ sln)
{
    int b = blockIdx.x, c = threadIdx.x;
    const float* p = s + (size_t)b * 262144 + c;
    float acc = 0.f;
    for (int l = 0; l < 1024; ++l) acc += p[(size_t)l * 256];
    float pooled = acc * (1.f / 1024.f);
    __shared__ float rs[4], rq[4];
    float sum = pooled, sq = pooled * pooled;
    #pragma unroll
    for (int off = 1; off < 64; off <<= 1) {
        sum += __shfl_xor(sum, off);
        sq += __shfl_xor(sq, off);
    }
    int w = threadIdx.x >> 6;
    if ((threadIdx.x & 63) == 0) { rs[w] = sum; rq[w] = sq; }
    __syncthreads();
    sum = rs[0] + rs[1] + rs[2] + rs[3];
    sq = rq[0] + rq[1] + rq[2] + rq[3];
    float m = sum * (1.f / 256.f);
    float var = sq * (1.f / 256.f) - m * m;
    float rstd = rsqrtf(var + 1e-5f);
    sln[b * 256 + c] = (pooled - m) * rstd * nw[c] + nb[c];
}

// softmax over 1000 logits per b
__global__ __launch_bounds__(256) void softmax_kernel(float* __restrict__ out)
{
    int b = threadIdx.x >> 6, lane = threadIdx.x & 63;
    const float* lg = out + b * 1000;
    float v[16];
    float mx = -1e30f;
    #pragma unroll
    for (int j = 0; j < 16; ++j) {
        int i = lane + j * 64;
        v[j] = (i < 1000) ? lg[i] : -1e30f;
        mx = fmaxf(mx, v[j]);
    }
    #pragma unroll
    for (int off = 1; off < 64; off <<= 1) mx = fmaxf(mx, __shfl_xor(mx, off));
    float sum = 0.f;
    #pragma unroll
    for (int j = 0; j < 16; ++j) {
        int i = lane + j * 64;
        if (i < 1000) { v[j] = __expf(v[j] - mx); sum += v[j]; }
    }
    #pragma unroll
    for (int off = 1; off < 64; off <<= 1) sum += __shfl_xor(sum, off);
    float inv = 1.f / sum;
    float* so = out + 4000 + b * 1000;
    #pragma unroll
    for (int j = 0; j < 16; ++j) {
        int i = lane + j * 64;
        if (i < 1000) so[i] = v[j] * inv;
    }
}

// ---------------------------------------------------------------------------
extern "C" void kernel_launch(void* const* d_in, const int* in_sizes, int n_in,
                              void* d_out, int out_size, void* d_ws, size_t ws_size,
                              hipStream_t stream)
{
    const float* x    = (const float*)d_in[0];
    const float* c1w  = (const float*)d_in[1];
    const float* c1b  = (const float*)d_in[2];
    const float* g1   = (const float*)d_in[3];
    const float* b1   = (const float*)d_in[4];
    const float* c2w  = (const float*)d_in[5];
    const float* c2b  = (const float*)d_in[6];
    const float* g2   = (const float*)d_in[7];
    const float* b2   = (const float*)d_in[8];
    const float* pw   = (const float*)d_in[9];
    const float* pb   = (const float*)d_in[10];
    const float* g3   = (const float*)d_in[11];
    const float* b3   = (const float*)d_in[12];
    const float* ipw  = (const float*)d_in[13];
    const float* ipb  = (const float*)d_in[14];
    const float* cw   = (const float*)d_in[15];
    const float* cb   = (const float*)d_in[16];
    const float* xpw  = (const float*)d_in[17];
    const float* dpw  = (const float*)d_in[18];
    const float* dpb  = (const float*)d_in[19];
    const float* alog = (const float*)d_in[20];
    const float* dssm = (const float*)d_in[21];
    const float* opw  = (const float*)d_in[22];
    const float* opb  = (const float*)d_in[23];
    const float* lnw  = (const float*)d_in[24];
    const float* lnb  = (const float*)d_in[25];
    const float* nw   = (const float*)d_in[26];
    const float* nb   = (const float*)d_in[27];
    const float* fcw  = (const float*)d_in[28];
    const float* fcb  = (const float*)d_in[29];
    float* out = (float*)d_out;
    float* wsf = (float*)d_ws;

    // ---- workspace layout (fl = float offsets), audited lifetimes ----
    // [0        , 1048576 )  s_    fp32 [4096,256]            persistent
    // [1048576  , 1572864 )  sb    bf16 [4096,256]            persistent
    // [1572864  , 3670016 )  xi    fp32 [4096,512]  | h2b bf16 [16384,256] | delta fp32 | obuf fp32
    // [3670016  , 4718592 )  resb  bf16 [4096,512]  (1048576 fl)
    // [4718592  , 6815744 )  u_    fp32 [4,512,1024]| h1b bf16 [16384,128]
    // [6815744  , 8912896 )  xl    fp32 [4096,512]  | Apb bf16 [4096,1024] | ybb bf16 [4096,512]
    // [8912896  , 9043968 )  xdbl  fp32 [4096,32]
    // [9043968  , 9109504 )  Btb   fp32 [4,16,1024]
    // [9109504  , 9175040 )  Ctb   fp32 [4,16,1024]
    // [9175040  , 9699328 )  ipwb  bf16 [4,1024,256]
    // [9699328  , 9961472 )  opwb  bf16 [4,256,512]
    // [9961472  , 10108928)  w2b   bf16 [256,1152]
    // [10108928 , 10240000)  pwTb  bf16 [256,1024]
    // [10240000 , 10241024)  sln   fp32 [4,256]
    // [10241024 , 10503168)  Psum  fp32 [4,128,64,8]
    // [10503168 , 10765312)  hFsum fp32 [4,128,64,8]    total 43.1 MB
    float*  s_   = wsf;
    ushort* sb   = (ushort*)(wsf + 1048576);
    float*  xi   = wsf + 1572864;
    ushort* h2b  = (ushort*)(wsf + 1572864);
    float*  delta= wsf + 1572864;
    float*  obuf = wsf + 1572864;
    ushort* resb = (ushort*)(wsf + 3670016);
    float*  u_   = wsf + 4718592;
    ushort* h1b  = (ushort*)(wsf + 4718592);
    float*  xl   = wsf + 6815744;
    ushort* Apb  = (ushort*)(wsf + 6815744);
    ushort* ybb  = (ushort*)(wsf + 6815744);
    float*  xdbl = wsf + 8912896;
    float*  Btb  = wsf + 9043968;
    float*  Ctb  = wsf + 9109504;
    ushort* ipwb = (ushort*)(wsf + 9175040);
    ushort* opwb = (ushort*)(wsf + 9699328);
    ushort* w2b  = (ushort*)(wsf + 9961472);
    ushort* pwTb = (ushort*)(wsf + 10108928);
    float*  sln  = wsf + 10240000;
    float*  Psum = wsf + 10241024;
    float*  hFsum= wsf + 10503168;

    // --- weight conversions ---
    hipLaunchKernelGGL(cvt_bf16, dim3(4096), dim3(256), 0, stream, ipw, ipwb, 1048576);
    hipLaunchKernelGGL(cvt_bf16, dim3(2048), dim3(256), 0, stream, opw, opwb, 524288);
    hipLaunchKernelGGL(w2b_kernel, dim3(1152), dim3(256), 0, stream, c2w, w2b);
    hipLaunchKernelGGL(pwTb_kernel, dim3(1024), dim3(256), 0, stream, pw, pwTb);

    // --- conv stem ---
    hipLaunchKernelGGL(conv1_nhwc, dim3(256), dim3(256), 0, stream, x, c1w, c1b, g1, b1, h1b);
    hipLaunchKernelGGL(conv2_mfma, dim3(128, 2), dim3(256), 0, stream, h1b, w2b, c2b, g2, b2, h2b);
    hipLaunchKernelGGL(im2col_bf16, dim3(2048), dim3(256), 0, stream, h2b, Apb);
    hipLaunchKernelGGL((mfma_gemm_bt<2>), dim3(32, 2), dim3(256), 0, stream,
                       Apb, 1024, pwTb, 1024, pb, g3, b3, s_, sb, 256, 1024);

    // --- mamba blocks ---
    for (int i = 0; i < 4; ++i) {
        const ushort* ipwb_i = ipwb + (size_t)i * 1024 * 256;
        const float*  ipb_i  = ipb + i * 1024;
        const float*  cw_i   = cw + i * 512 * 4;
        const float*  cb_i   = cb + i * 512;
        const float*  xpw_i  = xpw + (size_t)i * 64 * 512;
        const float*  dpw_i  = dpw + (size_t)i * 512 * 32;
        const float*  dpb_i  = dpb + i * 512;
        const float*  alog_i = alog + (size_t)i * 512 * 16;
        const float*  dssm_i = dssm + i * 512;
        const ushort* opwb_i = opwb + (size_t)i * 256 * 512;
        const float*  opb_i  = opb + i * 256;
        const float*  lnw_i  = lnw + i * 256;
        const float*  lnb_i  = lnb + i * 256;

        // in_proj (bf16 MFMA): xi fp32 + silu(res) bf16
        hipLaunchKernelGGL((mfma_gemm_bt<3>), dim3(32, 8), dim3(256), 0, stream,
                           sb, 256, ipwb_i, 256, ipb_i, nullptr, nullptr, xi, resb, 0, 256);
        hipLaunchKernelGGL(dwconv_dual, dim3(512), dim3(256), 0, stream, xi, cw_i, cb_i, xl, u_);
        // x_proj (fp32) with fused B/C transpose
        hipLaunchKernelGGL((gemm_kernel<64, 64, 16, 4, 4>), dim3(64, 1), dim3(256), 0, stream,
                           xl, 512, xpw_i, 512, nullptr, xdbl, 32, Btb, Ctb,
                           4096, 64, 512, 0, 2);
        // dt_proj (fp32) + softplus, transposed store -> delta[b,d,l]
        hipLaunchKernelGGL((gemm_kernel<64, 64, 16, 4, 4>), dim3(64, 8), dim3(256), 0, stream,
                           xdbl, 32, dpw_i, 32, dpb_i, delta, 512, nullptr, nullptr,
                           4096, 512, 32, 2, 1);
        // chunked scan: pass1 summaries, pass2 full + gate -> ybb bf16
        hipLaunchKernelGGL(scan_part1, dim3(1024), dim3(256), 0, stream,
                           delta, u_, Btb, alog_i, Psum, hFsum);
        hipLaunchKernelGGL(scan_part2, dim3(1024), dim3(256), 0, stream,
                           delta, u_, Btb, Ctb, alog_i, dssm_i, resb, ybb, Psum, hFsum);
        // out_proj (bf16 MFMA) -> obuf fp32
        hipLaunchKernelGGL((mfma_gemm_bt<0>), dim3(32, 2), dim3(256), 0, stream,
                           ybb, 512, opwb_i, 512, opb_i, nullptr, nullptr, obuf, nullptr, 256, 512);
        hipLaunchKernelGGL(ln_res_kernel, dim3(1024), dim3(256), 0, stream,
                           obuf, lnw_i, lnb_i, s_, sb);
    }

    // --- head ---
    hipLaunchKernelGGL(pool_ln_kernel, dim3(4), dim3(256), 0, stream, s_, nw, nb, sln);
    hipLaunchKernelGGL((gemm_kernel<64, 64, 16, 4, 4>), dim3(1, 16), dim3(256), 0, stream,
                       sln, 256, fcw, 256, fcb, out, 1000, nullptr, nullptr,
                       4, 1000, 256, 0, 0);
    hipLaunchKernelGGL(softmax_kernel, dim3(1), dim3(256), 0, stream, out);
}